// Round 3
// baseline (962.111 us; speedup 1.0000x reference)
//
#include <hip/hip_runtime.h>
#include <hip/hip_bf16.h>

// ---------- types ----------
using short8 = __attribute__((ext_vector_type(8))) short;
using f32x4  = __attribute__((ext_vector_type(4))) float;

// f32 -> bf16 round-to-nearest-even
__device__ __forceinline__ unsigned short f2bf(float f) {
    union { float f; unsigned u; } x; x.f = f;
    unsigned r = x.u + 0x7FFFu + ((x.u >> 16) & 1u);
    return (unsigned short)(r >> 16);
}

// ---------- mask dtype detector ----------
// flag bit0: some u32 >1 (not int32 0/1); bit1: some u32 >1 and != 0x3F800000 (=> byte bool)
__global__ void detect_mask_kernel(const unsigned int* __restrict__ m, int* __restrict__ flag) {
    if (threadIdx.x == 0) *flag = 0;
    __syncthreads();
    unsigned v = m[threadIdx.x];
    if (v > 1u) {
        atomicOr(flag, 1);
        if (v != 0x3F800000u) atomicOr(flag, 2);
    }
}

// ---------- pack mask into bitmask: Mb[word] = 64 bits, bit l = (elem wid*64+l) != 0 ----------
__global__ __launch_bounds__(256) void maskpack_kernel(
    const void* __restrict__ mask, const int* __restrict__ flag,
    unsigned long long* __restrict__ Mb)
{
    const size_t gid = (size_t)blockIdx.x * 256 + threadIdx.x;
    const size_t wid = gid >> 6;
    const int l = (int)(gid & 63);
    const int fl = *flag;
    unsigned v;
    if (fl & 2) v = ((const unsigned char*)mask)[wid * 64 + l];
    else        v = ((const unsigned int*)mask)[wid * 64 + l];
    unsigned long long b = __ballot(v != 0u);
    if (l == 0) Mb[wid] = b;
}

// ---------- transpose-convert W (f32 [k][n]) -> Wt (bf16 [n][k]), 1024x1024, z in 0..3 ----------
__global__ __launch_bounds__(256) void wconv_kernel(
    const float* __restrict__ W0, const float* __restrict__ W1,
    const float* __restrict__ W2, const float* __restrict__ W3,
    unsigned short* __restrict__ Wt)
{
    const int z = blockIdx.z;
    const float* W = (z == 0) ? W0 : ((z == 1) ? W1 : ((z == 2) ? W2 : W3));
    unsigned short* O = Wt + (size_t)z * 1024 * 1024;
    __shared__ float tile[64][68];
    const int t = threadIdx.x;
    const int k0 = blockIdx.x * 64, n0 = blockIdx.y * 64;
    const int rr = t >> 4, cc = t & 15;
#pragma unroll
    for (int i = 0; i < 4; i++) {
        int row = rr + i * 16;
        float4 v = *reinterpret_cast<const float4*>(W + (size_t)(k0 + row) * 1024 + n0 + cc * 4);
        *reinterpret_cast<float4*>(&tile[row][cc * 4]) = v;
    }
    __syncthreads();
#pragma unroll
    for (int i = 0; i < 4; i++) {
        int rn = rr + i * 16;
        ushort4 ov;
        ov.x = f2bf(tile[cc * 4 + 0][rn]);
        ov.y = f2bf(tile[cc * 4 + 1][rn]);
        ov.z = f2bf(tile[cc * 4 + 2][rn]);
        ov.w = f2bf(tile[cc * 4 + 3][rn]);
        *reinterpret_cast<ushort4*>(O + (size_t)(n0 + rn) * 1024 + k0 + cc * 4) = ov;
    }
}

// ---------- convert f32 A -> bf16 A, 3 x 8M elements ----------
__global__ __launch_bounds__(256) void aconv_kernel(
    const float* __restrict__ Aq, const float* __restrict__ Ak, const float* __restrict__ Av,
    unsigned short* __restrict__ Out)
{
    const int z = blockIdx.y;
    const float* A = (z == 0) ? Aq : ((z == 1) ? Ak : Av);
    unsigned short* O = Out + (size_t)z * 8192 * 1024;
    size_t i = ((size_t)blockIdx.x * 256 + threadIdx.x) * 8;
    float4 v0 = *reinterpret_cast<const float4*>(A + i);
    float4 v1 = *reinterpret_cast<const float4*>(A + i + 4);
    short8 o;
    o[0] = (short)f2bf(v0.x); o[1] = (short)f2bf(v0.y);
    o[2] = (short)f2bf(v0.z); o[3] = (short)f2bf(v0.w);
    o[4] = (short)f2bf(v1.x); o[5] = (short)f2bf(v1.y);
    o[6] = (short)f2bf(v1.z); o[7] = (short)f2bf(v1.w);
    *reinterpret_cast<short8*>(O + i) = o;
}

// ---------- projection GEMM (bf16 A): Out_z = A_z @ W_z + b_z -> bf16 [b][h][n][64] ----------
__global__ __launch_bounds__(256) void proj_bf_kernel(
    const unsigned short* __restrict__ Abf,  // [3][8192][1024] bf16
    const unsigned short* __restrict__ Wt,   // [3][1024 n][1024 k] bf16
    const float* __restrict__ bq, const float* __restrict__ bk, const float* __restrict__ bv,
    unsigned short* __restrict__ Out)        // [3][8][16][1024][64]
{
    const int z = blockIdx.z;
    const unsigned short* A = Abf + (size_t)z * 8192 * 1024;
    const float* bias = (z == 0) ? bq : ((z == 1) ? bk : bv);
    const unsigned short* Wz = Wt + (size_t)z * 1024 * 1024;
    unsigned short* Oz = Out + (size_t)z * 8 * 16 * 1024 * 64;

    const int tid = threadIdx.x;
    const int w = tid >> 6, l = tid & 63;
    const int l16 = l & 15, g = l >> 4;
    const int rbase = blockIdx.x * 128 + w * 32;
    const int cbase = blockIdx.y * 64;

    f32x4 acc[2][4];
#pragma unroll
    for (int i = 0; i < 2; i++)
#pragma unroll
        for (int j = 0; j < 4; j++) acc[i][j] = (f32x4){0.f, 0.f, 0.f, 0.f};

#pragma unroll 2
    for (int k0 = 0; k0 < 1024; k0 += 32) {
        short8 a[2];
#pragma unroll
        for (int rf = 0; rf < 2; rf++)
            a[rf] = *reinterpret_cast<const short8*>(A + (size_t)(rbase + rf * 16 + l16) * 1024 + k0 + g * 8);
        short8 bfr[4];
#pragma unroll
        for (int cf = 0; cf < 4; cf++)
            bfr[cf] = *reinterpret_cast<const short8*>(Wz + (size_t)(cbase + cf * 16 + l16) * 1024 + k0 + g * 8);
#pragma unroll
        for (int rf = 0; rf < 2; rf++)
#pragma unroll
            for (int cf = 0; cf < 4; cf++)
                acc[rf][cf] = __builtin_amdgcn_mfma_f32_16x16x32_bf16(a[rf], bfr[cf], acc[rf][cf], 0, 0, 0);
    }

#pragma unroll
    for (int rf = 0; rf < 2; rf++)
#pragma unroll
        for (int cf = 0; cf < 4; cf++)
#pragma unroll
            for (int r = 0; r < 4; r++) {
                int row = rbase + rf * 16 + g * 4 + r;
                int col = cbase + cf * 16 + l16;
                float val = acc[rf][cf][r] + bias[col];
                int bb = row >> 10, n = row & 1023;
                int h = col >> 6, d = col & 63;
                Oz[(((size_t)(bb * 16 + h)) * 1024 + n) * 64 + d] = f2bf(val);
            }
}

// ---------- projection GEMM (f32 A fallback, converts in-loop) ----------
__global__ __launch_bounds__(256) void proj_f32_kernel(
    const float* __restrict__ Aq, const float* __restrict__ Ak, const float* __restrict__ Av,
    const unsigned short* __restrict__ Wt,
    const float* __restrict__ bq, const float* __restrict__ bk, const float* __restrict__ bv,
    unsigned short* __restrict__ Out)
{
    const int z = blockIdx.z;
    const float* A = (z == 0) ? Aq : ((z == 1) ? Ak : Av);
    const float* bias = (z == 0) ? bq : ((z == 1) ? bk : bv);
    const unsigned short* Wz = Wt + (size_t)z * 1024 * 1024;
    unsigned short* Oz = Out + (size_t)z * 8 * 16 * 1024 * 64;

    const int tid = threadIdx.x;
    const int w = tid >> 6, l = tid & 63;
    const int l16 = l & 15, g = l >> 4;
    const int rbase = blockIdx.x * 128 + w * 32;
    const int cbase = blockIdx.y * 64;

    f32x4 acc[2][4];
#pragma unroll
    for (int i = 0; i < 2; i++)
#pragma unroll
        for (int j = 0; j < 4; j++) acc[i][j] = (f32x4){0.f, 0.f, 0.f, 0.f};

#pragma unroll 2
    for (int k0 = 0; k0 < 1024; k0 += 32) {
        short8 a[2];
#pragma unroll
        for (int rf = 0; rf < 2; rf++) {
            const float* ap = A + (size_t)(rbase + rf * 16 + l16) * 1024 + k0 + g * 8;
            float4 v0 = *reinterpret_cast<const float4*>(ap);
            float4 v1 = *reinterpret_cast<const float4*>(ap + 4);
            short8 av;
            av[0] = (short)f2bf(v0.x); av[1] = (short)f2bf(v0.y);
            av[2] = (short)f2bf(v0.z); av[3] = (short)f2bf(v0.w);
            av[4] = (short)f2bf(v1.x); av[5] = (short)f2bf(v1.y);
            av[6] = (short)f2bf(v1.z); av[7] = (short)f2bf(v1.w);
            a[rf] = av;
        }
        short8 bfr[4];
#pragma unroll
        for (int cf = 0; cf < 4; cf++)
            bfr[cf] = *reinterpret_cast<const short8*>(Wz + (size_t)(cbase + cf * 16 + l16) * 1024 + k0 + g * 8);
#pragma unroll
        for (int rf = 0; rf < 2; rf++)
#pragma unroll
            for (int cf = 0; cf < 4; cf++)
                acc[rf][cf] = __builtin_amdgcn_mfma_f32_16x16x32_bf16(a[rf], bfr[cf], acc[rf][cf], 0, 0, 0);
    }

#pragma unroll
    for (int rf = 0; rf < 2; rf++)
#pragma unroll
        for (int cf = 0; cf < 4; cf++)
#pragma unroll
            for (int r = 0; r < 4; r++) {
                int row = rbase + rf * 16 + g * 4 + r;
                int col = cbase + cf * 16 + l16;
                float val = acc[rf][cf][r] + bias[col];
                int bb = row >> 10, n = row & 1023;
                int h = col >> 6, d = col & 63;
                Oz[(((size_t)(bb * 16 + h)) * 1024 + n) * 64 + d] = f2bf(val);
            }
}

// ---------- transpose V: Vs [bh][k][64 d] -> Vt [bh][64 d][1024 k] ----------
__global__ __launch_bounds__(256) void vtrans_kernel(
    const unsigned short* __restrict__ Vs, unsigned short* __restrict__ Vt)
{
    const int bh = blockIdx.y;
    const int k0 = blockIdx.x * 64;
    const unsigned short* In = Vs + (size_t)bh * 1024 * 64;
    unsigned short* O = Vt + (size_t)bh * 64 * 1024;
    __shared__ unsigned short tile[64][72];
    const int t = threadIdx.x;
    {
        const int row = t >> 3;
        const int c8 = (t & 7) * 8;
#pragma unroll
        for (int i = 0; i < 2; i++) {
            int r = row + i * 32;
            short8 v = *reinterpret_cast<const short8*>(In + (size_t)(k0 + r) * 64 + c8);
            *reinterpret_cast<short8*>(&tile[r][c8]) = v;
        }
    }
    __syncthreads();
    {
        const int rd = t >> 4, c4 = (t & 15) * 4;
#pragma unroll
        for (int i = 0; i < 4; i++) {
            int d = rd + i * 16;
            ushort4 ov;
            ov.x = tile[c4 + 0][d];
            ov.y = tile[c4 + 1][d];
            ov.z = tile[c4 + 2][d];
            ov.w = tile[c4 + 3][d];
            *reinterpret_cast<ushort4*>(O + (size_t)d * 1024 + k0 + c4) = ov;
        }
    }
}

// ---------- fused attention: pipelined streaming (attw+maskbits prefetch one tile ahead) ----------
__global__ __launch_bounds__(256) void attn_kernel(
    const unsigned short* __restrict__ Qs,   // [bh][1024][64]
    const unsigned short* __restrict__ Ks,   // [bh][1024][64]
    const unsigned short* __restrict__ Vt,   // [bh][64 d][1024 k]
    const float* __restrict__ attw,          // [bh][1024][1024]
    const unsigned long long* __restrict__ Mb, // [bh*1024 rows][16 words]
    unsigned short* __restrict__ AO)         // [b][q][h*64+d] bf16
{
    const int b = blockIdx.z, h = blockIdx.y;
    const int qbase = blockIdx.x * 64;
    const int tid = threadIdx.x, w = tid >> 6, l = tid & 63, l16 = l & 15, g = l >> 4;
    const int bh = b * 16 + h;
    const unsigned short* Qbh = Qs + (size_t)bh * 65536;
    const unsigned short* Kbh = Ks + (size_t)bh * 65536;
    const unsigned short* Vbh = Vt + (size_t)bh * 65536;
    const int myq = qbase + w * 16 + l16;
    const float* wrow = attw + ((size_t)bh * 1024 + myq) * 1024;
    const unsigned long long* mrow = Mb + ((size_t)bh * 1024 + myq) * 16;

    __shared__ unsigned short P[4][16][80];   // per-wave [q 16][k 64], pad 80 (4-way max on b128 reads)

    short8 qf[2];
#pragma unroll
    for (int ks = 0; ks < 2; ks++)
        qf[ks] = *reinterpret_cast<const short8*>(Qbh + (size_t)myq * 64 + ks * 32 + g * 8);

    // prefetch tile 0 streaming operands
    float4 wv[4];
#pragma unroll
    for (int cf = 0; cf < 4; cf++)
        wv[cf] = *reinterpret_cast<const float4*>(wrow + cf * 16 + g * 4);
    unsigned long long mb = mrow[0];

    f32x4 accO[4];
#pragma unroll
    for (int j = 0; j < 4; j++) accO[j] = (f32x4){0.f, 0.f, 0.f, 0.f};
    float den = 0.f;

    for (int kt = 0; kt < 16; kt++) {
        const int kb = kt * 64;
        // 1) K,V fragment loads for this tile (L1/L2-resident; issue BEFORE streaming so
        //    the QK/PV vmcnt waits never drain the long-latency prefetch below)
        short8 kf[4][2], vf[4][2];
#pragma unroll
        for (int cf = 0; cf < 4; cf++)
#pragma unroll
            for (int ks = 0; ks < 2; ks++) {
                kf[cf][ks] = *reinterpret_cast<const short8*>(
                    Kbh + (size_t)(kb + cf * 16 + l16) * 64 + ks * 32 + g * 8);
                vf[cf][ks] = *reinterpret_cast<const short8*>(
                    Vbh + (size_t)(cf * 16 + l16) * 1024 + kb + ks * 32 + g * 8);
            }
        // 2) streaming prefetch for next tile (HBM, ~900cy — hidden under QK+softmax+PV)
        const int ktn = (kt + 1) & 15;
        float4 wvn[4];
#pragma unroll
        for (int cf = 0; cf < 4; cf++)
            wvn[cf] = *reinterpret_cast<const float4*>(wrow + ktn * 64 + cf * 16 + g * 4);
        unsigned long long mbn = mrow[ktn];

        // 3) QK^T (transposed operands: S^T fragments, k-cols lane-local)
        f32x4 s[4];
#pragma unroll
        for (int j = 0; j < 4; j++) s[j] = (f32x4){0.f, 0.f, 0.f, 0.f};
#pragma unroll
        for (int cf = 0; cf < 4; cf++)
#pragma unroll
            for (int ks = 0; ks < 2; ks++)
                s[cf] = __builtin_amdgcn_mfma_f32_16x16x32_bf16(kf[cf][ks], qf[ks], s[cf], 0, 0, 0);

        // 4) softmax numerators from CURRENT regs (loaded last iteration)
#pragma unroll
        for (int cf = 0; cf < 4; cf++) {
            unsigned mn = (unsigned)(mb >> (cf * 16 + g * 4)) & 0xFu;
            float p0 = (mn & 1u) ? 0.f : __expf(s[cf][0] * 0.125f * wv[cf].x);
            float p1 = (mn & 2u) ? 0.f : __expf(s[cf][1] * 0.125f * wv[cf].y);
            float p2 = (mn & 4u) ? 0.f : __expf(s[cf][2] * 0.125f * wv[cf].z);
            float p3 = (mn & 8u) ? 0.f : __expf(s[cf][3] * 0.125f * wv[cf].w);
            den += p0 + p1 + p2 + p3;
            ushort4 pw;
            pw.x = f2bf(p0); pw.y = f2bf(p1); pw.z = f2bf(p2); pw.w = f2bf(p3);
            *reinterpret_cast<ushort4*>(&P[w][l16][cf * 16 + g * 4]) = pw;
        }
        // 5) PV (wave-private P -> no block barrier; compiler inserts lgkmcnt)
#pragma unroll
        for (int ks = 0; ks < 2; ks++) {
            short8 pf = *reinterpret_cast<const short8*>(&P[w][l16][ks * 32 + g * 8]);
#pragma unroll
            for (int cf = 0; cf < 4; cf++)
                accO[cf] = __builtin_amdgcn_mfma_f32_16x16x32_bf16(pf, vf[cf][ks], accO[cf], 0, 0, 0);
        }
        // 6) rotate streaming regs
#pragma unroll
        for (int cf = 0; cf < 4; cf++) wv[cf] = wvn[cf];
        mb = mbn;
    }

    // den: partial row-sum for q-row l16 over this lane's 16 k-cols/tile; reduce across g-groups
    den += __shfl_xor(den, 16);
    den += __shfl_xor(den, 32);

#pragma unroll
    for (int r = 0; r < 4; r++) {
        float dr = __shfl(den, g * 4 + r);
        float inv = 1.0f / dr;
#pragma unroll
        for (int cf = 0; cf < 4; cf++) {
            int qrow = qbase + w * 16 + g * 4 + r;
            int col = h * 64 + cf * 16 + l16;
            AO[((size_t)b * 1024 + qrow) * 1024 + col] = f2bf(accO[cf][r] * inv);
        }
    }
}

// ---------- output projection: d_out = AO (bf16 8192x1024) @ Wo + bo (f32 out) ----------
__global__ __launch_bounds__(256) void outproj_kernel(
    const unsigned short* __restrict__ Ain,
    const unsigned short* __restrict__ Wto,
    const float* __restrict__ bo,
    float* __restrict__ Out)
{
    const int tid = threadIdx.x;
    const int w = tid >> 6, l = tid & 63;
    const int l16 = l & 15, g = l >> 4;
    const int rbase = blockIdx.x * 128 + w * 32;
    const int cbase = blockIdx.y * 64;

    f32x4 acc[2][4];
#pragma unroll
    for (int i = 0; i < 2; i++)
#pragma unroll
        for (int j = 0; j < 4; j++) acc[i][j] = (f32x4){0.f, 0.f, 0.f, 0.f};

#pragma unroll 2
    for (int k0 = 0; k0 < 1024; k0 += 32) {
        short8 a[2];
#pragma unroll
        for (int rf = 0; rf < 2; rf++)
            a[rf] = *reinterpret_cast<const short8*>(Ain + (size_t)(rbase + rf * 16 + l16) * 1024 + k0 + g * 8);
        short8 bfr[4];
#pragma unroll
        for (int cf = 0; cf < 4; cf++)
            bfr[cf] = *reinterpret_cast<const short8*>(Wto + (size_t)(cbase + cf * 16 + l16) * 1024 + k0 + g * 8);
#pragma unroll
        for (int rf = 0; rf < 2; rf++)
#pragma unroll
            for (int cf = 0; cf < 4; cf++)
                acc[rf][cf] = __builtin_amdgcn_mfma_f32_16x16x32_bf16(a[rf], bfr[cf], acc[rf][cf], 0, 0, 0);
    }

#pragma unroll
    for (int rf = 0; rf < 2; rf++)
#pragma unroll
        for (int cf = 0; cf < 4; cf++)
#pragma unroll
            for (int r = 0; r < 4; r++) {
                int row = rbase + rf * 16 + g * 4 + r;
                int col = cbase + cf * 16 + l16;
                Out[(size_t)row * 1024 + col] = acc[rf][cf][r] + bo[col];
            }
}

extern "C" void kernel_launch(void* const* d_in, const int* in_sizes, int n_in,
                              void* d_out, int out_size, void* d_ws, size_t ws_size,
                              hipStream_t stream)
{
    const float* queries = (const float*)d_in[0];
    const float* keys    = (const float*)d_in[1];
    const float* values  = (const float*)d_in[2];
    const void*  mask    = d_in[3];
    const float* attw    = (const float*)d_in[4];
    const float* Wq = (const float*)d_in[5];
    const float* bq = (const float*)d_in[6];
    const float* Wk = (const float*)d_in[7];
    const float* bk = (const float*)d_in[8];
    const float* Wv = (const float*)d_in[9];
    const float* bv = (const float*)d_in[10];
    const float* Wo = (const float*)d_in[11];
    const float* bo = (const float*)d_in[12];

    char* ws = (char*)d_ws;
    int* flag = (int*)ws;
    unsigned short* base = (unsigned short*)(ws + 256);
    const size_t M8 = (size_t)8 * 1024 * 1024;   // elements per 16MB bf16 buffer
    unsigned short* Qs  = base;
    unsigned short* Ksb = base + M8;
    unsigned short* Vs  = base + 2 * M8;         // raw V proj; dead after vtrans -> reused for Mb
    unsigned short* Vtb = base + 3 * M8;
    unsigned short* AO  = base + 4 * M8;
    unsigned short* Wt  = base + 5 * M8;                         // 4 x 1M elements (8 MB)
    unsigned short* Abf = base + 5 * M8 + 4 * 1024 * 1024;       // 3 x 8M elements (48 MB), optional
    unsigned long long* Mb = (unsigned long long*)Vs;            // 2M u64 = 16 MB, aliases Vs
    const size_t need_abf = 256 + (5 * M8 + 4 * 1024 * 1024 + 3 * M8) * sizeof(unsigned short);
    const bool useAbf = ws_size >= need_abf;

    detect_mask_kernel<<<1, 256, 0, stream>>>((const unsigned int*)mask, flag);
    wconv_kernel<<<dim3(16, 16, 4), 256, 0, stream>>>(Wq, Wk, Wv, Wo, Wt);
    if (useAbf) {
        aconv_kernel<<<dim3(4096, 3), 256, 0, stream>>>(queries, keys, values, Abf);
        proj_bf_kernel<<<dim3(64, 16, 3), 256, 0, stream>>>(Abf, Wt, bq, bk, bv, Qs);
    } else {
        proj_f32_kernel<<<dim3(64, 16, 3), 256, 0, stream>>>(queries, keys, values, Wt, bq, bk, bv, Qs);
    }
    vtrans_kernel<<<dim3(16, 128), 256, 0, stream>>>(Vs, Vtb);
    // Vs is dead from here; pack mask bits into its storage
    maskpack_kernel<<<dim3(524288), 256, 0, stream>>>(mask, flag, Mb);
    attn_kernel<<<dim3(16, 16, 8), 256, 0, stream>>>(Qs, Ksb, Vtb, attw, Mb, AO);
    outproj_kernel<<<dim3(64, 16), 256, 0, stream>>>(AO, Wt + (size_t)3 * 1024 * 1024, bo, (float*)d_out);
}

// Round 4
// 829.215 us; speedup vs baseline: 1.1603x; 1.1603x over previous
//
#include <hip/hip_runtime.h>
#include <hip/hip_bf16.h>

// ---------- types ----------
using short8 = __attribute__((ext_vector_type(8))) short;
using f32x4  = __attribute__((ext_vector_type(4))) float;

// f32 -> bf16 round-to-nearest-even
__device__ __forceinline__ unsigned short f2bf(float f) {
    union { float f; unsigned u; } x; x.f = f;
    unsigned r = x.u + 0x7FFFu + ((x.u >> 16) & 1u);
    return (unsigned short)(r >> 16);
}

// ---------- mask dtype detector ----------
// flag bit0: some u32 >1 (not int32 0/1); bit1: some u32 >1 and != 0x3F800000 (=> byte bool)
__global__ void detect_mask_kernel(const unsigned int* __restrict__ m, int* __restrict__ flag) {
    if (threadIdx.x == 0) *flag = 0;
    __syncthreads();
    unsigned v = m[threadIdx.x];
    if (v > 1u) {
        atomicOr(flag, 1);
        if (v != 0x3F800000u) atomicOr(flag, 2);
    }
}

// ---------- pack mask into bitmask (grid-stride; 2048 blocks, 4 words per wave per iter) ----------
__global__ __launch_bounds__(256) void maskpack_kernel(
    const void* __restrict__ mask, const int* __restrict__ flag,
    unsigned long long* __restrict__ Mb, int nwords)
{
    const int l = threadIdx.x & 63;
    const int gwave = (int)((blockIdx.x * 256 + threadIdx.x) >> 6);
    const int nw = (int)((gridDim.x * 256) >> 6);
    const bool bytem = ((*flag) & 2) != 0;
    const unsigned char* m8 = (const unsigned char*)mask;
    const unsigned int* m32 = (const unsigned int*)mask;
    for (int w0 = gwave * 4; w0 < nwords; w0 += nw * 4) {
        unsigned v[4];
#pragma unroll
        for (int u = 0; u < 4; u++) {
            size_t e = (size_t)(w0 + u) * 64 + l;
            v[u] = bytem ? (unsigned)m8[e] : m32[e];
        }
#pragma unroll
        for (int u = 0; u < 4; u++) {
            unsigned long long b = __ballot(v[u] != 0u);
            if (l == 0) Mb[w0 + u] = b;
        }
    }
}

// ---------- transpose-convert W (f32 [k][n]) -> Wt (bf16 [n][k]), 1024x1024, z in 0..3 ----------
__global__ __launch_bounds__(256) void wconv_kernel(
    const float* __restrict__ W0, const float* __restrict__ W1,
    const float* __restrict__ W2, const float* __restrict__ W3,
    unsigned short* __restrict__ Wt)
{
    const int z = blockIdx.z;
    const float* W = (z == 0) ? W0 : ((z == 1) ? W1 : ((z == 2) ? W2 : W3));
    unsigned short* O = Wt + (size_t)z * 1024 * 1024;
    __shared__ float tile[64][68];
    const int t = threadIdx.x;
    const int k0 = blockIdx.x * 64, n0 = blockIdx.y * 64;
    const int rr = t >> 4, cc = t & 15;
#pragma unroll
    for (int i = 0; i < 4; i++) {
        int row = rr + i * 16;
        float4 v = *reinterpret_cast<const float4*>(W + (size_t)(k0 + row) * 1024 + n0 + cc * 4);
        *reinterpret_cast<float4*>(&tile[row][cc * 4]) = v;
    }
    __syncthreads();
#pragma unroll
    for (int i = 0; i < 4; i++) {
        int rn = rr + i * 16;
        ushort4 ov;
        ov.x = f2bf(tile[cc * 4 + 0][rn]);
        ov.y = f2bf(tile[cc * 4 + 1][rn]);
        ov.z = f2bf(tile[cc * 4 + 2][rn]);
        ov.w = f2bf(tile[cc * 4 + 3][rn]);
        *reinterpret_cast<ushort4*>(O + (size_t)(n0 + rn) * 1024 + k0 + cc * 4) = ov;
    }
}

// ---------- convert f32 A -> bf16 A, 3 x 8M elements ----------
__global__ __launch_bounds__(256) void aconv_kernel(
    const float* __restrict__ Aq, const float* __restrict__ Ak, const float* __restrict__ Av,
    unsigned short* __restrict__ Out)
{
    const int z = blockIdx.y;
    const float* A = (z == 0) ? Aq : ((z == 1) ? Ak : Av);
    unsigned short* O = Out + (size_t)z * 8192 * 1024;
    size_t i = ((size_t)blockIdx.x * 256 + threadIdx.x) * 8;
    float4 v0 = *reinterpret_cast<const float4*>(A + i);
    float4 v1 = *reinterpret_cast<const float4*>(A + i + 4);
    short8 o;
    o[0] = (short)f2bf(v0.x); o[1] = (short)f2bf(v0.y);
    o[2] = (short)f2bf(v0.z); o[3] = (short)f2bf(v0.w);
    o[4] = (short)f2bf(v1.x); o[5] = (short)f2bf(v1.y);
    o[6] = (short)f2bf(v1.z); o[7] = (short)f2bf(v1.w);
    *reinterpret_cast<short8*>(O + i) = o;
}

// ---------- projection GEMM (bf16 A), K double-buffered ----------
__global__ __launch_bounds__(256, 4) void proj_bf_kernel(
    const unsigned short* __restrict__ Abf,  // [3][8192][1024] bf16
    const unsigned short* __restrict__ Wt,   // [3][1024 n][1024 k] bf16
    const float* __restrict__ bq, const float* __restrict__ bk, const float* __restrict__ bv,
    unsigned short* __restrict__ Out)        // [3][8][16][1024][64]
{
    const int z = blockIdx.z;
    const unsigned short* A = Abf + (size_t)z * 8192 * 1024;
    const float* bias = (z == 0) ? bq : ((z == 1) ? bk : bv);
    const unsigned short* Wz = Wt + (size_t)z * 1024 * 1024;
    unsigned short* Oz = Out + (size_t)z * 8 * 16 * 1024 * 64;

    const int tid = threadIdx.x;
    const int w = tid >> 6, l = tid & 63;
    const int l16 = l & 15, g = l >> 4;
    const int rbase = blockIdx.x * 128 + w * 32;
    const int cbase = blockIdx.y * 64;

    f32x4 acc[2][4];
#pragma unroll
    for (int i = 0; i < 2; i++)
#pragma unroll
        for (int j = 0; j < 4; j++) acc[i][j] = (f32x4){0.f, 0.f, 0.f, 0.f};

    const unsigned short* Ap = A + (size_t)(rbase + l16) * 1024 + g * 8;
    const unsigned short* Wp = Wz + (size_t)(cbase + l16) * 1024 + g * 8;

    short8 a0[2], b0[4], a1[2], b1[4];
#pragma unroll
    for (int rf = 0; rf < 2; rf++) a0[rf] = *reinterpret_cast<const short8*>(Ap + rf * 16 * 1024);
#pragma unroll
    for (int cf = 0; cf < 4; cf++) b0[cf] = *reinterpret_cast<const short8*>(Wp + cf * 16 * 1024);

    for (int k0 = 0; k0 < 1024; k0 += 64) {
#pragma unroll
        for (int rf = 0; rf < 2; rf++) a1[rf] = *reinterpret_cast<const short8*>(Ap + rf * 16 * 1024 + k0 + 32);
#pragma unroll
        for (int cf = 0; cf < 4; cf++) b1[cf] = *reinterpret_cast<const short8*>(Wp + cf * 16 * 1024 + k0 + 32);
#pragma unroll
        for (int rf = 0; rf < 2; rf++)
#pragma unroll
            for (int cf = 0; cf < 4; cf++)
                acc[rf][cf] = __builtin_amdgcn_mfma_f32_16x16x32_bf16(a0[rf], b0[cf], acc[rf][cf], 0, 0, 0);
        const int kn = (k0 + 64) & 1023;
#pragma unroll
        for (int rf = 0; rf < 2; rf++) a0[rf] = *reinterpret_cast<const short8*>(Ap + rf * 16 * 1024 + kn);
#pragma unroll
        for (int cf = 0; cf < 4; cf++) b0[cf] = *reinterpret_cast<const short8*>(Wp + cf * 16 * 1024 + kn);
#pragma unroll
        for (int rf = 0; rf < 2; rf++)
#pragma unroll
            for (int cf = 0; cf < 4; cf++)
                acc[rf][cf] = __builtin_amdgcn_mfma_f32_16x16x32_bf16(a1[rf], b1[cf], acc[rf][cf], 0, 0, 0);
    }

#pragma unroll
    for (int rf = 0; rf < 2; rf++)
#pragma unroll
        for (int cf = 0; cf < 4; cf++)
#pragma unroll
            for (int r = 0; r < 4; r++) {
                int row = rbase + rf * 16 + g * 4 + r;
                int col = cbase + cf * 16 + l16;
                float val = acc[rf][cf][r] + bias[col];
                int bb = row >> 10, n = row & 1023;
                int h = col >> 6, d = col & 63;
                Oz[(((size_t)(bb * 16 + h)) * 1024 + n) * 64 + d] = f2bf(val);
            }
}

// ---------- projection GEMM (f32 A fallback, converts in-loop) ----------
__global__ __launch_bounds__(256) void proj_f32_kernel(
    const float* __restrict__ Aq, const float* __restrict__ Ak, const float* __restrict__ Av,
    const unsigned short* __restrict__ Wt,
    const float* __restrict__ bq, const float* __restrict__ bk, const float* __restrict__ bv,
    unsigned short* __restrict__ Out)
{
    const int z = blockIdx.z;
    const float* A = (z == 0) ? Aq : ((z == 1) ? Ak : Av);
    const float* bias = (z == 0) ? bq : ((z == 1) ? bk : bv);
    const unsigned short* Wz = Wt + (size_t)z * 1024 * 1024;
    unsigned short* Oz = Out + (size_t)z * 8 * 16 * 1024 * 64;

    const int tid = threadIdx.x;
    const int w = tid >> 6, l = tid & 63;
    const int l16 = l & 15, g = l >> 4;
    const int rbase = blockIdx.x * 128 + w * 32;
    const int cbase = blockIdx.y * 64;

    f32x4 acc[2][4];
#pragma unroll
    for (int i = 0; i < 2; i++)
#pragma unroll
        for (int j = 0; j < 4; j++) acc[i][j] = (f32x4){0.f, 0.f, 0.f, 0.f};

#pragma unroll 2
    for (int k0 = 0; k0 < 1024; k0 += 32) {
        short8 a[2];
#pragma unroll
        for (int rf = 0; rf < 2; rf++) {
            const float* ap = A + (size_t)(rbase + rf * 16 + l16) * 1024 + k0 + g * 8;
            float4 v0 = *reinterpret_cast<const float4*>(ap);
            float4 v1 = *reinterpret_cast<const float4*>(ap + 4);
            short8 av;
            av[0] = (short)f2bf(v0.x); av[1] = (short)f2bf(v0.y);
            av[2] = (short)f2bf(v0.z); av[3] = (short)f2bf(v0.w);
            av[4] = (short)f2bf(v1.x); av[5] = (short)f2bf(v1.y);
            av[6] = (short)f2bf(v1.z); av[7] = (short)f2bf(v1.w);
            a[rf] = av;
        }
        short8 bfr[4];
#pragma unroll
        for (int cf = 0; cf < 4; cf++)
            bfr[cf] = *reinterpret_cast<const short8*>(Wz + (size_t)(cbase + cf * 16 + l16) * 1024 + k0 + g * 8);
#pragma unroll
        for (int rf = 0; rf < 2; rf++)
#pragma unroll
            for (int cf = 0; cf < 4; cf++)
                acc[rf][cf] = __builtin_amdgcn_mfma_f32_16x16x32_bf16(a[rf], bfr[cf], acc[rf][cf], 0, 0, 0);
    }

#pragma unroll
    for (int rf = 0; rf < 2; rf++)
#pragma unroll
        for (int cf = 0; cf < 4; cf++)
#pragma unroll
            for (int r = 0; r < 4; r++) {
                int row = rbase + rf * 16 + g * 4 + r;
                int col = cbase + cf * 16 + l16;
                float val = acc[rf][cf][r] + bias[col];
                int bb = row >> 10, n = row & 1023;
                int h = col >> 6, d = col & 63;
                Oz[(((size_t)(bb * 16 + h)) * 1024 + n) * 64 + d] = f2bf(val);
            }
}

// ---------- transpose V: Vs [bh][k][64 d] -> Vt [bh][64 d][1024 k] ----------
__global__ __launch_bounds__(256) void vtrans_kernel(
    const unsigned short* __restrict__ Vs, unsigned short* __restrict__ Vt)
{
    const int bh = blockIdx.y;
    const int k0 = blockIdx.x * 64;
    const unsigned short* In = Vs + (size_t)bh * 1024 * 64;
    unsigned short* O = Vt + (size_t)bh * 64 * 1024;
    __shared__ unsigned short tile[64][72];
    const int t = threadIdx.x;
    {
        const int row = t >> 3;
        const int c8 = (t & 7) * 8;
#pragma unroll
        for (int i = 0; i < 2; i++) {
            int r = row + i * 32;
            short8 v = *reinterpret_cast<const short8*>(In + (size_t)(k0 + r) * 64 + c8);
            *reinterpret_cast<short8*>(&tile[r][c8]) = v;
        }
    }
    __syncthreads();
    {
        const int rd = t >> 4, c4 = (t & 15) * 4;
#pragma unroll
        for (int i = 0; i < 4; i++) {
            int d = rd + i * 16;
            ushort4 ov;
            ov.x = tile[c4 + 0][d];
            ov.y = tile[c4 + 1][d];
            ov.z = tile[c4 + 2][d];
            ov.w = tile[c4 + 3][d];
            *reinterpret_cast<ushort4*>(O + (size_t)d * 1024 + k0 + c4) = ov;
        }
    }
}

// ---------- fused attention: loads issued in consumption order, 2-tile attw lead ----------
__global__ __launch_bounds__(256, 3) void attn_kernel(
    const unsigned short* __restrict__ Qs,     // [bh][1024][64]
    const unsigned short* __restrict__ Ks,     // [bh][1024][64]
    const unsigned short* __restrict__ Vt,     // [bh][64 d][1024 k]
    const float* __restrict__ attw,            // [bh][1024][1024]
    const unsigned long long* __restrict__ Mb, // [bh*1024 rows][16 words]
    unsigned short* __restrict__ AO)           // [b][q][h*64+d] bf16
{
    const int b = blockIdx.z, h = blockIdx.y;
    const int qbase = blockIdx.x * 64;
    const int tid = threadIdx.x, w = tid >> 6, l = tid & 63, l16 = l & 15, g = l >> 4;
    const int bh = b * 16 + h;
    const unsigned short* Qbh = Qs + (size_t)bh * 65536;
    const unsigned short* Kbh = Ks + (size_t)bh * 65536;
    const unsigned short* Vbh = Vt + (size_t)bh * 65536;
    const int myq = qbase + w * 16 + l16;
    const float* wrow = attw + ((size_t)bh * 1024 + myq) * 1024;
    const unsigned long long* mrow = Mb + ((size_t)bh * 1024 + myq) * 16;

    __shared__ unsigned short P[4][16][72];   // per-wave [q 16][k 64]

    short8 qf[2];
#pragma unroll
    for (int ks = 0; ks < 2; ks++)
        qf[ks] = *reinterpret_cast<const short8*>(Qbh + (size_t)myq * 64 + ks * 32 + g * 8);

    short8 kf[4][2], vf[4][2];
    float4 wvA[4], wvB[4];
    unsigned long long mbA, mbB;

    // prologue: issue in steady-state consumption order: kf(0), vf(0), wv(0), wv(1)
#pragma unroll
    for (int cf = 0; cf < 4; cf++)
#pragma unroll
        for (int ks = 0; ks < 2; ks++)
            kf[cf][ks] = *reinterpret_cast<const short8*>(Kbh + (size_t)(cf * 16 + l16) * 64 + ks * 32 + g * 8);
#pragma unroll
    for (int cf = 0; cf < 4; cf++)
#pragma unroll
        for (int ks = 0; ks < 2; ks++)
            vf[cf][ks] = *reinterpret_cast<const short8*>(Vbh + (size_t)(cf * 16 + l16) * 1024 + ks * 32 + g * 8);
#pragma unroll
    for (int cf = 0; cf < 4; cf++)
        wvA[cf] = *reinterpret_cast<const float4*>(wrow + cf * 16 + g * 4);
    mbA = mrow[0];
#pragma unroll
    for (int cf = 0; cf < 4; cf++)
        wvB[cf] = *reinterpret_cast<const float4*>(wrow + 64 + cf * 16 + g * 4);
    mbB = mrow[1];

    f32x4 accO[4];
#pragma unroll
    for (int j = 0; j < 4; j++) accO[j] = (f32x4){0.f, 0.f, 0.f, 0.f};
    float den = 0.f;

    // per-iteration schedule (issue order == consumption order; waits never drain
    // younger prefetches):
    //   QK(kf cur) -> issue kf(next) -> softmax(wv cur) -> issue vf(next)
    //   -> PV(vf cur) -> issue wv(cur slot, tile kt+2)
#define ATTN_ITER(KT, WVC, MBC)                                                            \
    {                                                                                      \
        const int kb = (KT) * 64;                                                          \
        const int kbn = (((KT) + 1) & 15) * 64;                                            \
        f32x4 s[4];                                                                        \
        _Pragma("unroll")                                                                  \
        for (int j = 0; j < 4; j++) s[j] = (f32x4){0.f, 0.f, 0.f, 0.f};                    \
        _Pragma("unroll")                                                                  \
        for (int cf = 0; cf < 4; cf++)                                                     \
            _Pragma("unroll")                                                              \
            for (int ks = 0; ks < 2; ks++)                                                 \
                s[cf] = __builtin_amdgcn_mfma_f32_16x16x32_bf16(kf[cf][ks], qf[ks], s[cf], 0, 0, 0); \
        _Pragma("unroll")                                                                  \
        for (int cf = 0; cf < 4; cf++)                                                     \
            _Pragma("unroll")                                                              \
            for (int ks = 0; ks < 2; ks++)                                                 \
                kf[cf][ks] = *reinterpret_cast<const short8*>(                             \
                    Kbh + (size_t)(kbn + cf * 16 + l16) * 64 + ks * 32 + g * 8);           \
        _Pragma("unroll")                                                                  \
        for (int cf = 0; cf < 4; cf++) {                                                   \
            unsigned mn = (unsigned)((MBC) >> (cf * 16 + g * 4)) & 0xFu;                   \
            float p0 = (mn & 1u) ? 0.f : __expf(s[cf][0] * 0.125f * (WVC)[cf].x);          \
            float p1 = (mn & 2u) ? 0.f : __expf(s[cf][1] * 0.125f * (WVC)[cf].y);          \
            float p2 = (mn & 4u) ? 0.f : __expf(s[cf][2] * 0.125f * (WVC)[cf].z);          \
            float p3 = (mn & 8u) ? 0.f : __expf(s[cf][3] * 0.125f * (WVC)[cf].w);          \
            den += p0 + p1 + p2 + p3;                                                      \
            ushort4 pw;                                                                    \
            pw.x = f2bf(p0); pw.y = f2bf(p1); pw.z = f2bf(p2); pw.w = f2bf(p3);            \
            *reinterpret_cast<ushort4*>(&P[w][l16][cf * 16 + g * 4]) = pw;                 \
        }                                                                                  \
        short8 pf0 = *reinterpret_cast<const short8*>(&P[w][l16][g * 8]);                  \
        short8 pf1 = *reinterpret_cast<const short8*>(&P[w][l16][32 + g * 8]);             \
        short8 vn[4][2];                                                                   \
        _Pragma("unroll")                                                                  \
        for (int cf = 0; cf < 4; cf++)                                                     \
            _Pragma("unroll")                                                              \
            for (int ks = 0; ks < 2; ks++)                                                 \
                vn[cf][ks] = *reinterpret_cast<const short8*>(                             \
                    Vbh + (size_t)(cf * 16 + l16) * 1024 + kbn + ks * 32 + g * 8);         \
        _Pragma("unroll")                                                                  \
        for (int cf = 0; cf < 4; cf++) {                                                   \
            accO[cf] = __builtin_amdgcn_mfma_f32_16x16x32_bf16(pf0, vf[cf][0], accO[cf], 0, 0, 0); \
            accO[cf] = __builtin_amdgcn_mfma_f32_16x16x32_bf16(pf1, vf[cf][1], accO[cf], 0, 0, 0); \
        }                                                                                  \
        _Pragma("unroll")                                                                  \
        for (int cf = 0; cf < 4; cf++)                                                     \
            _Pragma("unroll")                                                              \
            for (int ks = 0; ks < 2; ks++)                                                 \
                vf[cf][ks] = vn[cf][ks];                                                   \
        if ((KT) < 14) {                                                                   \
            const int kb2 = ((KT) + 2) * 64;                                               \
            _Pragma("unroll")                                                              \
            for (int cf = 0; cf < 4; cf++)                                                 \
                (WVC)[cf] = *reinterpret_cast<const float4*>(wrow + kb2 + cf * 16 + g * 4);\
            (MBC) = mrow[(KT) + 2];                                                        \
        }                                                                                  \
    }

    for (int kt2 = 0; kt2 < 16; kt2 += 2) {
        ATTN_ITER(kt2, wvA, mbA);
        ATTN_ITER(kt2 + 1, wvB, mbB);
    }
#undef ATTN_ITER

    den += __shfl_xor(den, 16);
    den += __shfl_xor(den, 32);

#pragma unroll
    for (int r = 0; r < 4; r++) {
        float dr = __shfl(den, g * 4 + r);
        float inv = 1.0f / dr;
#pragma unroll
        for (int cf = 0; cf < 4; cf++) {
            int qrow = qbase + w * 16 + g * 4 + r;
            int col = h * 64 + cf * 16 + l16;
            AO[((size_t)b * 1024 + qrow) * 1024 + col] = f2bf(accO[cf][r] * inv);
        }
    }
}

// ---------- output projection: d_out = AO (bf16 8192x1024) @ Wo + bo (f32 out), K dbuf ----------
__global__ __launch_bounds__(256, 4) void outproj_kernel(
    const unsigned short* __restrict__ Ain,
    const unsigned short* __restrict__ Wto,
    const float* __restrict__ bo,
    float* __restrict__ Out)
{
    const int tid = threadIdx.x;
    const int w = tid >> 6, l = tid & 63;
    const int l16 = l & 15, g = l >> 4;
    const int rbase = blockIdx.x * 128 + w * 32;
    const int cbase = blockIdx.y * 64;

    f32x4 acc[2][4];
#pragma unroll
    for (int i = 0; i < 2; i++)
#pragma unroll
        for (int j = 0; j < 4; j++) acc[i][j] = (f32x4){0.f, 0.f, 0.f, 0.f};

    const unsigned short* Ap = Ain + (size_t)(rbase + l16) * 1024 + g * 8;
    const unsigned short* Wp = Wto + (size_t)(cbase + l16) * 1024 + g * 8;

    short8 a0[2], b0[4], a1[2], b1[4];
#pragma unroll
    for (int rf = 0; rf < 2; rf++) a0[rf] = *reinterpret_cast<const short8*>(Ap + rf * 16 * 1024);
#pragma unroll
    for (int cf = 0; cf < 4; cf++) b0[cf] = *reinterpret_cast<const short8*>(Wp + cf * 16 * 1024);

    for (int k0 = 0; k0 < 1024; k0 += 64) {
#pragma unroll
        for (int rf = 0; rf < 2; rf++) a1[rf] = *reinterpret_cast<const short8*>(Ap + rf * 16 * 1024 + k0 + 32);
#pragma unroll
        for (int cf = 0; cf < 4; cf++) b1[cf] = *reinterpret_cast<const short8*>(Wp + cf * 16 * 1024 + k0 + 32);
#pragma unroll
        for (int rf = 0; rf < 2; rf++)
#pragma unroll
            for (int cf = 0; cf < 4; cf++)
                acc[rf][cf] = __builtin_amdgcn_mfma_f32_16x16x32_bf16(a0[rf], b0[cf], acc[rf][cf], 0, 0, 0);
        const int kn = (k0 + 64) & 1023;
#pragma unroll
        for (int rf = 0; rf < 2; rf++) a0[rf] = *reinterpret_cast<const short8*>(Ap + rf * 16 * 1024 + kn);
#pragma unroll
        for (int cf = 0; cf < 4; cf++) b0[cf] = *reinterpret_cast<const short8*>(Wp + cf * 16 * 1024 + kn);
#pragma unroll
        for (int rf = 0; rf < 2; rf++)
#pragma unroll
            for (int cf = 0; cf < 4; cf++)
                acc[rf][cf] = __builtin_amdgcn_mfma_f32_16x16x32_bf16(a1[rf], b1[cf], acc[rf][cf], 0, 0, 0);
    }

#pragma unroll
    for (int rf = 0; rf < 2; rf++)
#pragma unroll
        for (int cf = 0; cf < 4; cf++)
#pragma unroll
            for (int r = 0; r < 4; r++) {
                int row = rbase + rf * 16 + g * 4 + r;
                int col = cbase + cf * 16 + l16;
                Out[(size_t)row * 1024 + col] = acc[rf][cf][r] + bo[col];
            }
}

extern "C" void kernel_launch(void* const* d_in, const int* in_sizes, int n_in,
                              void* d_out, int out_size, void* d_ws, size_t ws_size,
                              hipStream_t stream)
{
    const float* queries = (const float*)d_in[0];
    const float* keys    = (const float*)d_in[1];
    const float* values  = (const float*)d_in[2];
    const void*  mask    = d_in[3];
    const float* attw    = (const float*)d_in[4];
    const float* Wq = (const float*)d_in[5];
    const float* bq = (const float*)d_in[6];
    const float* Wk = (const float*)d_in[7];
    const float* bk = (const float*)d_in[8];
    const float* Wv = (const float*)d_in[9];
    const float* bv = (const float*)d_in[10];
    const float* Wo = (const float*)d_in[11];
    const float* bo = (const float*)d_in[12];

    char* ws = (char*)d_ws;
    int* flag = (int*)ws;
    unsigned short* base = (unsigned short*)(ws + 256);
    const size_t M8 = (size_t)8 * 1024 * 1024;   // elements per 16MB bf16 buffer
    unsigned short* Qs  = base;
    unsigned short* Ksb = base + M8;
    unsigned short* Vs  = base + 2 * M8;         // raw V proj; dead after vtrans -> reused for Mb
    unsigned short* Vtb = base + 3 * M8;
    unsigned short* AO  = base + 4 * M8;
    unsigned short* Wt  = base + 5 * M8;                         // 4 x 1M elements (8 MB)
    unsigned short* Abf = base + 5 * M8 + 4 * 1024 * 1024;       // 3 x 8M elements (48 MB), optional
    unsigned long long* Mb = (unsigned long long*)Vs;            // 2M u64 = 16 MB, aliases Vs
    const size_t need_abf = 256 + (5 * M8 + 4 * 1024 * 1024 + 3 * M8) * sizeof(unsigned short);
    const bool useAbf = ws_size >= need_abf;

    detect_mask_kernel<<<1, 256, 0, stream>>>((const unsigned int*)mask, flag);
    wconv_kernel<<<dim3(16, 16, 4), 256, 0, stream>>>(Wq, Wk, Wv, Wo, Wt);
    if (useAbf) {
        aconv_kernel<<<dim3(4096, 3), 256, 0, stream>>>(queries, keys, values, Abf);
        proj_bf_kernel<<<dim3(64, 16, 3), 256, 0, stream>>>(Abf, Wt, bq, bk, bv, Qs);
    } else {
        proj_f32_kernel<<<dim3(64, 16, 3), 256, 0, stream>>>(queries, keys, values, Wt, bq, bk, bv, Qs);
    }
    vtrans_kernel<<<dim3(16, 128), 256, 0, stream>>>(Vs, Vtb);
    // Vs is dead from here; pack mask bits into its storage (2048 blocks, grid-stride)
    maskpack_kernel<<<dim3(2048), 256, 0, stream>>>(mask, flag, Mb, 2 * 1024 * 1024);
    attn_kernel<<<dim3(16, 16, 8), 256, 0, stream>>>(Qs, Ksb, Vtb, attw, Mb, AO);
    outproj_kernel<<<dim3(64, 16), 256, 0, stream>>>(AO, Wt + (size_t)3 * 1024 * 1024, bo, (float*)d_out);
}

// Round 5
// 673.717 us; speedup vs baseline: 1.4281x; 1.2308x over previous
//
#include <hip/hip_runtime.h>
#include <hip/hip_bf16.h>

// ---------- types ----------
using short8 = __attribute__((ext_vector_type(8))) short;
using f32x4  = __attribute__((ext_vector_type(4))) float;

// f32 -> bf16 round-to-nearest-even
__device__ __forceinline__ unsigned short f2bf(float f) {
    union { float f; unsigned u; } x; x.f = f;
    unsigned r = x.u + 0x7FFFu + ((x.u >> 16) & 1u);
    return (unsigned short)(r >> 16);
}

// async global->LDS, 16B per lane; lds base must be wave-uniform
__device__ __forceinline__ void gload_lds16(const void* g, void* l) {
    __builtin_amdgcn_global_load_lds(
        (const __attribute__((address_space(1))) unsigned int*)g,
        (__attribute__((address_space(3))) unsigned int*)l, 16, 0, 0);
}

// ---------- mask dtype detector ----------
__global__ void detect_mask_kernel(const unsigned int* __restrict__ m, int* __restrict__ flag) {
    if (threadIdx.x == 0) *flag = 0;
    __syncthreads();
    unsigned v = m[threadIdx.x];
    if (v > 1u) {
        atomicOr(flag, 1);
        if (v != 0x3F800000u) atomicOr(flag, 2);
    }
}

// ---------- pack mask into bitmask (grid-stride) ----------
__global__ __launch_bounds__(256) void maskpack_kernel(
    const void* __restrict__ mask, const int* __restrict__ flag,
    unsigned long long* __restrict__ Mb, int nwords)
{
    const int l = threadIdx.x & 63;
    const int gwave = (int)((blockIdx.x * 256 + threadIdx.x) >> 6);
    const int nw = (int)((gridDim.x * 256) >> 6);
    const bool bytem = ((*flag) & 2) != 0;
    const unsigned char* m8 = (const unsigned char*)mask;
    const unsigned int* m32 = (const unsigned int*)mask;
    for (int w0 = gwave * 4; w0 < nwords; w0 += nw * 4) {
        unsigned v[4];
#pragma unroll
        for (int u = 0; u < 4; u++) {
            size_t e = (size_t)(w0 + u) * 64 + l;
            v[u] = bytem ? (unsigned)m8[e] : m32[e];
        }
#pragma unroll
        for (int u = 0; u < 4; u++) {
            unsigned long long b = __ballot(v[u] != 0u);
            if (l == 0) Mb[w0 + u] = b;
        }
    }
}

// ---------- transpose-convert W (f32 [k][n]) -> Wt (bf16 [n][k]) ----------
__global__ __launch_bounds__(256) void wconv_kernel(
    const float* __restrict__ W0, const float* __restrict__ W1,
    const float* __restrict__ W2, const float* __restrict__ W3,
    unsigned short* __restrict__ Wt)
{
    const int z = blockIdx.z;
    const float* W = (z == 0) ? W0 : ((z == 1) ? W1 : ((z == 2) ? W2 : W3));
    unsigned short* O = Wt + (size_t)z * 1024 * 1024;
    __shared__ float tile[64][68];
    const int t = threadIdx.x;
    const int k0 = blockIdx.x * 64, n0 = blockIdx.y * 64;
    const int rr = t >> 4, cc = t & 15;
#pragma unroll
    for (int i = 0; i < 4; i++) {
        int row = rr + i * 16;
        float4 v = *reinterpret_cast<const float4*>(W + (size_t)(k0 + row) * 1024 + n0 + cc * 4);
        *reinterpret_cast<float4*>(&tile[row][cc * 4]) = v;
    }
    __syncthreads();
#pragma unroll
    for (int i = 0; i < 4; i++) {
        int rn = rr + i * 16;
        ushort4 ov;
        ov.x = f2bf(tile[cc * 4 + 0][rn]);
        ov.y = f2bf(tile[cc * 4 + 1][rn]);
        ov.z = f2bf(tile[cc * 4 + 2][rn]);
        ov.w = f2bf(tile[cc * 4 + 3][rn]);
        *reinterpret_cast<ushort4*>(O + (size_t)(n0 + rn) * 1024 + k0 + cc * 4) = ov;
    }
}

// ---------- convert f32 A -> bf16 A ----------
__global__ __launch_bounds__(256) void aconv_kernel(
    const float* __restrict__ Aq, const float* __restrict__ Ak, const float* __restrict__ Av,
    unsigned short* __restrict__ Out)
{
    const int z = blockIdx.y;
    const float* A = (z == 0) ? Aq : ((z == 1) ? Ak : Av);
    unsigned short* O = Out + (size_t)z * 8192 * 1024;
    size_t i = ((size_t)blockIdx.x * 256 + threadIdx.x) * 8;
    float4 v0 = *reinterpret_cast<const float4*>(A + i);
    float4 v1 = *reinterpret_cast<const float4*>(A + i + 4);
    short8 o;
    o[0] = (short)f2bf(v0.x); o[1] = (short)f2bf(v0.y);
    o[2] = (short)f2bf(v0.z); o[3] = (short)f2bf(v0.w);
    o[4] = (short)f2bf(v1.x); o[5] = (short)f2bf(v1.y);
    o[6] = (short)f2bf(v1.z); o[7] = (short)f2bf(v1.w);
    *reinterpret_cast<short8*>(O + i) = o;
}

// ---------- projection GEMM (bf16 A), K double-buffered ----------
__global__ __launch_bounds__(256, 4) void proj_bf_kernel(
    const unsigned short* __restrict__ Abf,
    const unsigned short* __restrict__ Wt,
    const float* __restrict__ bq, const float* __restrict__ bk, const float* __restrict__ bv,
    unsigned short* __restrict__ Out)
{
    const int z = blockIdx.z;
    const unsigned short* A = Abf + (size_t)z * 8192 * 1024;
    const float* bias = (z == 0) ? bq : ((z == 1) ? bk : bv);
    const unsigned short* Wz = Wt + (size_t)z * 1024 * 1024;
    unsigned short* Oz = Out + (size_t)z * 8 * 16 * 1024 * 64;

    const int tid = threadIdx.x;
    const int w = tid >> 6, l = tid & 63;
    const int l16 = l & 15, g = l >> 4;
    const int rbase = blockIdx.x * 128 + w * 32;
    const int cbase = blockIdx.y * 64;

    f32x4 acc[2][4];
#pragma unroll
    for (int i = 0; i < 2; i++)
#pragma unroll
        for (int j = 0; j < 4; j++) acc[i][j] = (f32x4){0.f, 0.f, 0.f, 0.f};

    const unsigned short* Ap = A + (size_t)(rbase + l16) * 1024 + g * 8;
    const unsigned short* Wp = Wz + (size_t)(cbase + l16) * 1024 + g * 8;

    short8 a0[2], b0[4], a1[2], b1[4];
#pragma unroll
    for (int rf = 0; rf < 2; rf++) a0[rf] = *reinterpret_cast<const short8*>(Ap + rf * 16 * 1024);
#pragma unroll
    for (int cf = 0; cf < 4; cf++) b0[cf] = *reinterpret_cast<const short8*>(Wp + cf * 16 * 1024);

    for (int k0 = 0; k0 < 1024; k0 += 64) {
#pragma unroll
        for (int rf = 0; rf < 2; rf++) a1[rf] = *reinterpret_cast<const short8*>(Ap + rf * 16 * 1024 + k0 + 32);
#pragma unroll
        for (int cf = 0; cf < 4; cf++) b1[cf] = *reinterpret_cast<const short8*>(Wp + cf * 16 * 1024 + k0 + 32);
#pragma unroll
        for (int rf = 0; rf < 2; rf++)
#pragma unroll
            for (int cf = 0; cf < 4; cf++)
                acc[rf][cf] = __builtin_amdgcn_mfma_f32_16x16x32_bf16(a0[rf], b0[cf], acc[rf][cf], 0, 0, 0);
        const int kn = (k0 + 64) & 1023;
#pragma unroll
        for (int rf = 0; rf < 2; rf++) a0[rf] = *reinterpret_cast<const short8*>(Ap + rf * 16 * 1024 + kn);
#pragma unroll
        for (int cf = 0; cf < 4; cf++) b0[cf] = *reinterpret_cast<const short8*>(Wp + cf * 16 * 1024 + kn);
#pragma unroll
        for (int rf = 0; rf < 2; rf++)
#pragma unroll
            for (int cf = 0; cf < 4; cf++)
                acc[rf][cf] = __builtin_amdgcn_mfma_f32_16x16x32_bf16(a1[rf], b1[cf], acc[rf][cf], 0, 0, 0);
    }

#pragma unroll
    for (int rf = 0; rf < 2; rf++)
#pragma unroll
        for (int cf = 0; cf < 4; cf++)
#pragma unroll
            for (int r = 0; r < 4; r++) {
                int row = rbase + rf * 16 + g * 4 + r;
                int col = cbase + cf * 16 + l16;
                float val = acc[rf][cf][r] + bias[col];
                int bb = row >> 10, n = row & 1023;
                int h = col >> 6, d = col & 63;
                Oz[(((size_t)(bb * 16 + h)) * 1024 + n) * 64 + d] = f2bf(val);
            }
}

// ---------- projection GEMM (f32 A fallback) ----------
__global__ __launch_bounds__(256) void proj_f32_kernel(
    const float* __restrict__ Aq, const float* __restrict__ Ak, const float* __restrict__ Av,
    const unsigned short* __restrict__ Wt,
    const float* __restrict__ bq, const float* __restrict__ bk, const float* __restrict__ bv,
    unsigned short* __restrict__ Out)
{
    const int z = blockIdx.z;
    const float* A = (z == 0) ? Aq : ((z == 1) ? Ak : Av);
    const float* bias = (z == 0) ? bq : ((z == 1) ? bk : bv);
    const unsigned short* Wz = Wt + (size_t)z * 1024 * 1024;
    unsigned short* Oz = Out + (size_t)z * 8 * 16 * 1024 * 64;

    const int tid = threadIdx.x;
    const int w = tid >> 6, l = tid & 63;
    const int l16 = l & 15, g = l >> 4;
    const int rbase = blockIdx.x * 128 + w * 32;
    const int cbase = blockIdx.y * 64;

    f32x4 acc[2][4];
#pragma unroll
    for (int i = 0; i < 2; i++)
#pragma unroll
        for (int j = 0; j < 4; j++) acc[i][j] = (f32x4){0.f, 0.f, 0.f, 0.f};

#pragma unroll 2
    for (int k0 = 0; k0 < 1024; k0 += 32) {
        short8 a[2];
#pragma unroll
        for (int rf = 0; rf < 2; rf++) {
            const float* ap = A + (size_t)(rbase + rf * 16 + l16) * 1024 + k0 + g * 8;
            float4 v0 = *reinterpret_cast<const float4*>(ap);
            float4 v1 = *reinterpret_cast<const float4*>(ap + 4);
            short8 av;
            av[0] = (short)f2bf(v0.x); av[1] = (short)f2bf(v0.y);
            av[2] = (short)f2bf(v0.z); av[3] = (short)f2bf(v0.w);
            av[4] = (short)f2bf(v1.x); av[5] = (short)f2bf(v1.y);
            av[6] = (short)f2bf(v1.z); av[7] = (short)f2bf(v1.w);
            a[rf] = av;
        }
        short8 bfr[4];
#pragma unroll
        for (int cf = 0; cf < 4; cf++)
            bfr[cf] = *reinterpret_cast<const short8*>(Wz + (size_t)(cbase + cf * 16 + l16) * 1024 + k0 + g * 8);
#pragma unroll
        for (int rf = 0; rf < 2; rf++)
#pragma unroll
            for (int cf = 0; cf < 4; cf++)
                acc[rf][cf] = __builtin_amdgcn_mfma_f32_16x16x32_bf16(a[rf], bfr[cf], acc[rf][cf], 0, 0, 0);
    }

#pragma unroll
    for (int rf = 0; rf < 2; rf++)
#pragma unroll
        for (int cf = 0; cf < 4; cf++)
#pragma unroll
            for (int r = 0; r < 4; r++) {
                int row = rbase + rf * 16 + g * 4 + r;
                int col = cbase + cf * 16 + l16;
                float val = acc[rf][cf][r] + bias[col];
                int bb = row >> 10, n = row & 1023;
                int h = col >> 6, d = col & 63;
                Oz[(((size_t)(bb * 16 + h)) * 1024 + n) * 64 + d] = f2bf(val);
            }
}

// ---------- transpose V: Vs [bh][k][64 d] -> Vt [bh][64 d][1024 k] ----------
__global__ __launch_bounds__(256) void vtrans_kernel(
    const unsigned short* __restrict__ Vs, unsigned short* __restrict__ Vt)
{
    const int bh = blockIdx.y;
    const int k0 = blockIdx.x * 64;
    const unsigned short* In = Vs + (size_t)bh * 1024 * 64;
    unsigned short* O = Vt + (size_t)bh * 64 * 1024;
    __shared__ unsigned short tile[64][72];
    const int t = threadIdx.x;
    {
        const int row = t >> 3;
        const int c8 = (t & 7) * 8;
#pragma unroll
        for (int i = 0; i < 2; i++) {
            int r = row + i * 32;
            short8 v = *reinterpret_cast<const short8*>(In + (size_t)(k0 + r) * 64 + c8);
            *reinterpret_cast<short8*>(&tile[r][c8]) = v;
        }
    }
    __syncthreads();
    {
        const int rd = t >> 4, c4 = (t & 15) * 4;
#pragma unroll
        for (int i = 0; i < 4; i++) {
            int d = rd + i * 16;
            ushort4 ov;
            ov.x = tile[c4 + 0][d];
            ov.y = tile[c4 + 1][d];
            ov.z = tile[c4 + 2][d];
            ov.w = tile[c4 + 3][d];
            *reinterpret_cast<ushort4*>(O + (size_t)d * 1024 + k0 + c4) = ov;
        }
    }
}

// ---------- fused attention: 8 waves, LDS-staged K/V (global_load_lds, swizzled),
// counted vmcnt(5) so the 2-tile-lead attw/mask stream is never drained ----------
__global__ __launch_bounds__(512, 4) void attn_kernel(
    const unsigned short* __restrict__ Qs,     // [bh][1024][64]
    const unsigned short* __restrict__ Ks,     // [bh][1024][64]
    const unsigned short* __restrict__ Vt,     // [bh][64 d][1024 k]
    const float* __restrict__ attw,            // [bh][1024][1024]
    const unsigned long long* __restrict__ Mb, // [bh*1024 rows][16 words]
    unsigned short* __restrict__ AO)           // [b][q][h*64+d] bf16
{
    // LDS: K dbuf @0/8192, V dbuf @16384/24576, P @32768 (per wave 16x72 ushort = 2304B)
    __shared__ char smem[51200];

    // XCD-bijective decode: 8 q-tiles sharing one (b,h) -> same XCD (K/V L2 locality)
    const int bid = blockIdx.x;
    const int xj = bid & 7, xp = bid >> 3;
    const int qt = xp & 7;
    const int gbh = (xp >> 3) * 8 + xj;        // = h + 16*b
    const int h = gbh & 15, b = gbh >> 4;
    const int bh = b * 16 + h;

    const int tid = threadIdx.x, w = tid >> 6, l = tid & 63, l16 = l & 15, g = l >> 4;
    const int myq = qt * 128 + w * 16 + l16;

    const unsigned short* Qbh = Qs + (size_t)bh * 65536;
    const char* Kb = (const char*)(Ks + (size_t)bh * 65536);
    const char* Vb = (const char*)(Vt + (size_t)bh * 65536);
    const float* wrow = attw + ((size_t)bh * 1024 + myq) * 1024;
    const unsigned long long* mrow = Mb + ((size_t)bh * 1024 + myq) * 16;

    // ---- staging geometry: 8KB tile, 8 waves x 1KB; linear LDS, pre-swizzled source
    const int srow = w * 8 + (l >> 3);                 // tile-local row staged by this lane
    const int sinn = ((l & 7) * 16) ^ (((l >> 3) & 7) << 4);
    const char* gK = Kb + (size_t)srow * 128 + sinn;   // +8192 per tile
    const char* gV = Vb + (size_t)srow * 2048 + sinn;  // +128 per tile
    char* ldsK0w = smem + 0     + w * 1024;
    char* ldsK1w = smem + 8192  + w * 1024;
    char* ldsV0w = smem + 16384 + w * 1024;
    char* ldsV1w = smem + 24576 + w * 1024;

    // ---- ds_read addresses (swizzled): row=cf*16+l16 => row&7 == l16&7
    const int rswz = (l16 & 7) << 4;
    char* kaddrA = smem + l16 * 128 + ((g * 16) ^ rswz);        // ks=0; +cf*2048, +BUF*8192
    char* kaddrB = smem + l16 * 128 + ((64 + g * 16) ^ rswz);   // ks=1
    char* pw = smem + 32768 + w * 2304 + l16 * 144 + g * 8;     // P write: +cf*32
    char* pr = smem + 32768 + w * 2304 + l16 * 144 + g * 16;    // P read:  +ks*64

    short8 qf0 = *reinterpret_cast<const short8*>(Qbh + (size_t)myq * 64 + g * 8);
    short8 qf1 = *reinterpret_cast<const short8*>(Qbh + (size_t)myq * 64 + 32 + g * 8);

    float4 wvA[4], wvB[4];
    unsigned long long mbA, mbB;

    // prologue: stage tile0 (2 GLL) then wv(0), wv(1) (10 loads); retire staging only
    gload_lds16(gK, ldsK0w);
    gload_lds16(gV, ldsV0w);
    gK += 8192; gV += 128;
#pragma unroll
    for (int cf = 0; cf < 4; cf++)
        wvA[cf] = *reinterpret_cast<const float4*>(wrow + cf * 16 + g * 4);
    mbA = mrow[0];
#pragma unroll
    for (int cf = 0; cf < 4; cf++)
        wvB[cf] = *reinterpret_cast<const float4*>(wrow + 64 + cf * 16 + g * 4);
    mbB = mrow[1];
    asm volatile("s_waitcnt vmcnt(10)" ::: "memory");
    __builtin_amdgcn_s_barrier();
    __builtin_amdgcn_sched_barrier(0);

    f32x4 accO[4];
#pragma unroll
    for (int j = 0; j < 4; j++) accO[j] = (f32x4){0.f, 0.f, 0.f, 0.f};
    float den = 0.f;

    // per tile: [stage(t+1): 2 GLL] [QK+softmax using wv(t)] [refill wv(t+2): 5 loads]
    //           [PV] [vmcnt(5): retire wv(t+1)+stage(t+1), keep wv(t+2)] [barrier]
#define ATTN_ITER(KT, BUF, WVC, MBC)                                                        \
    {                                                                                       \
        if ((KT) < 15) {                                                                    \
            gload_lds16(gK, (BUF) ? ldsK0w : ldsK1w);                                       \
            gload_lds16(gV, (BUF) ? ldsV0w : ldsV1w);                                       \
        }                                                                                   \
        gK += 8192; gV += 128;                                                              \
        _Pragma("unroll")                                                                   \
        for (int cf = 0; cf < 4; cf++) {                                                    \
            short8 k0 = *reinterpret_cast<const short8*>(kaddrA + (BUF) * 8192 + cf * 2048);\
            short8 k1 = *reinterpret_cast<const short8*>(kaddrB + (BUF) * 8192 + cf * 2048);\
            f32x4 s = (f32x4){0.f, 0.f, 0.f, 0.f};                                          \
            s = __builtin_amdgcn_mfma_f32_16x16x32_bf16(k0, qf0, s, 0, 0, 0);               \
            s = __builtin_amdgcn_mfma_f32_16x16x32_bf16(k1, qf1, s, 0, 0, 0);               \
            unsigned mn = (unsigned)((MBC) >> (cf * 16 + g * 4)) & 0xFu;                    \
            float p0 = (mn & 1u) ? 0.f : __expf(s[0] * 0.125f * (WVC)[cf].x);               \
            float p1 = (mn & 2u) ? 0.f : __expf(s[1] * 0.125f * (WVC)[cf].y);               \
            float p2 = (mn & 4u) ? 0.f : __expf(s[2] * 0.125f * (WVC)[cf].z);               \
            float p3 = (mn & 8u) ? 0.f : __expf(s[3] * 0.125f * (WVC)[cf].w);               \
            den += p0 + p1 + p2 + p3;                                                       \
            ushort4 pwv;                                                                    \
            pwv.x = f2bf(p0); pwv.y = f2bf(p1); pwv.z = f2bf(p2); pwv.w = f2bf(p3);         \
            *reinterpret_cast<ushort4*>(pw + cf * 32) = pwv;                                \
        }                                                                                   \
        {                                                                                   \
            const int ktn = ((KT) + 2) & 15;                                                \
            _Pragma("unroll")                                                               \
            for (int cf = 0; cf < 4; cf++)                                                  \
                (WVC)[cf] = *reinterpret_cast<const float4*>(wrow + ktn * 64 + cf * 16 + g * 4); \
            (MBC) = mrow[ktn];                                                              \
        }                                                                                   \
        {                                                                                   \
            short8 pf0 = *reinterpret_cast<const short8*>(pr);                              \
            short8 pf1 = *reinterpret_cast<const short8*>(pr + 64);                         \
            _Pragma("unroll")                                                               \
            for (int cf = 0; cf < 4; cf++) {                                                \
                short8 v0 = *reinterpret_cast<const short8*>(kaddrA + 16384 + (BUF) * 8192 + cf * 2048); \
                short8 v1 = *reinterpret_cast<const short8*>(kaddrB + 16384 + (BUF) * 8192 + cf * 2048); \
                accO[cf] = __builtin_amdgcn_mfma_f32_16x16x32_bf16(pf0, v0, accO[cf], 0, 0, 0); \
                accO[cf] = __builtin_amdgcn_mfma_f32_16x16x32_bf16(pf1, v1, accO[cf], 0, 0, 0); \
            }                                                                               \
        }                                                                                   \
        asm volatile("s_waitcnt vmcnt(5)" ::: "memory");                                    \
        __builtin_amdgcn_s_barrier();                                                       \
        __builtin_amdgcn_sched_barrier(0);                                                  \
    }

    for (int kt2 = 0; kt2 < 16; kt2 += 2) {
        ATTN_ITER(kt2, 0, wvA, mbA);
        ATTN_ITER(kt2 + 1, 1, wvB, mbB);
    }
#undef ATTN_ITER

    den += __shfl_xor(den, 16);
    den += __shfl_xor(den, 32);

#pragma unroll
    for (int r = 0; r < 4; r++) {
        float dr = __shfl(den, g * 4 + r);
        float inv = 1.0f / dr;
#pragma unroll
        for (int cf = 0; cf < 4; cf++) {
            int qrow = qt * 128 + w * 16 + g * 4 + r;
            int col = h * 64 + cf * 16 + l16;
            AO[((size_t)b * 1024 + qrow) * 1024 + col] = f2bf(accO[cf][r] * inv);
        }
    }
}

// ---------- output projection: d_out = AO @ Wo + bo (f32 out), K dbuf ----------
__global__ __launch_bounds__(256, 4) void outproj_kernel(
    const unsigned short* __restrict__ Ain,
    const unsigned short* __restrict__ Wto,
    const float* __restrict__ bo,
    float* __restrict__ Out)
{
    const int tid = threadIdx.x;
    const int w = tid >> 6, l = tid & 63;
    const int l16 = l & 15, g = l >> 4;
    const int rbase = blockIdx.x * 128 + w * 32;
    const int cbase = blockIdx.y * 64;

    f32x4 acc[2][4];
#pragma unroll
    for (int i = 0; i < 2; i++)
#pragma unroll
        for (int j = 0; j < 4; j++) acc[i][j] = (f32x4){0.f, 0.f, 0.f, 0.f};

    const unsigned short* Ap = Ain + (size_t)(rbase + l16) * 1024 + g * 8;
    const unsigned short* Wp = Wto + (size_t)(cbase + l16) * 1024 + g * 8;

    short8 a0[2], b0[4], a1[2], b1[4];
#pragma unroll
    for (int rf = 0; rf < 2; rf++) a0[rf] = *reinterpret_cast<const short8*>(Ap + rf * 16 * 1024);
#pragma unroll
    for (int cf = 0; cf < 4; cf++) b0[cf] = *reinterpret_cast<const short8*>(Wp + cf * 16 * 1024);

    for (int k0 = 0; k0 < 1024; k0 += 64) {
#pragma unroll
        for (int rf = 0; rf < 2; rf++) a1[rf] = *reinterpret_cast<const short8*>(Ap + rf * 16 * 1024 + k0 + 32);
#pragma unroll
        for (int cf = 0; cf < 4; cf++) b1[cf] = *reinterpret_cast<const short8*>(Wp + cf * 16 * 1024 + k0 + 32);
#pragma unroll
        for (int rf = 0; rf < 2; rf++)
#pragma unroll
            for (int cf = 0; cf < 4; cf++)
                acc[rf][cf] = __builtin_amdgcn_mfma_f32_16x16x32_bf16(a0[rf], b0[cf], acc[rf][cf], 0, 0, 0);
        const int kn = (k0 + 64) & 1023;
#pragma unroll
        for (int rf = 0; rf < 2; rf++) a0[rf] = *reinterpret_cast<const short8*>(Ap + rf * 16 * 1024 + kn);
#pragma unroll
        for (int cf = 0; cf < 4; cf++) b0[cf] = *reinterpret_cast<const short8*>(Wp + cf * 16 * 1024 + kn);
#pragma unroll
        for (int rf = 0; rf < 2; rf++)
#pragma unroll
            for (int cf = 0; cf < 4; cf++)
                acc[rf][cf] = __builtin_amdgcn_mfma_f32_16x16x32_bf16(a1[rf], b1[cf], acc[rf][cf], 0, 0, 0);
    }

#pragma unroll
    for (int rf = 0; rf < 2; rf++)
#pragma unroll
        for (int cf = 0; cf < 4; cf++)
#pragma unroll
            for (int r = 0; r < 4; r++) {
                int row = rbase + rf * 16 + g * 4 + r;
                int col = cbase + cf * 16 + l16;
                Out[(size_t)row * 1024 + col] = acc[rf][cf][r] + bo[col];
            }
}

extern "C" void kernel_launch(void* const* d_in, const int* in_sizes, int n_in,
                              void* d_out, int out_size, void* d_ws, size_t ws_size,
                              hipStream_t stream)
{
    const float* queries = (const float*)d_in[0];
    const float* keys    = (const float*)d_in[1];
    const float* values  = (const float*)d_in[2];
    const void*  mask    = d_in[3];
    const float* attw    = (const float*)d_in[4];
    const float* Wq = (const float*)d_in[5];
    const float* bq = (const float*)d_in[6];
    const float* Wk = (const float*)d_in[7];
    const float* bk = (const float*)d_in[8];
    const float* Wv = (const float*)d_in[9];
    const float* bv = (const float*)d_in[10];
    const float* Wo = (const float*)d_in[11];
    const float* bo = (const float*)d_in[12];

    char* ws = (char*)d_ws;
    int* flag = (int*)ws;
    unsigned short* base = (unsigned short*)(ws + 256);
    const size_t M8 = (size_t)8 * 1024 * 1024;
    unsigned short* Qs  = base;
    unsigned short* Ksb = base + M8;
    unsigned short* Vs  = base + 2 * M8;         // raw V proj; dead after vtrans -> reused for Mb
    unsigned short* Vtb = base + 3 * M8;
    unsigned short* AO  = base + 4 * M8;
    unsigned short* Wt  = base + 5 * M8;
    unsigned short* Abf = base + 5 * M8 + 4 * 1024 * 1024;
    unsigned long long* Mb = (unsigned long long*)Vs;
    const size_t need_abf = 256 + (5 * M8 + 4 * 1024 * 1024 + 3 * M8) * sizeof(unsigned short);
    const bool useAbf = ws_size >= need_abf;

    detect_mask_kernel<<<1, 256, 0, stream>>>((const unsigned int*)mask, flag);
    wconv_kernel<<<dim3(16, 16, 4), 256, 0, stream>>>(Wq, Wk, Wv, Wo, Wt);
    if (useAbf) {
        aconv_kernel<<<dim3(4096, 3), 256, 0, stream>>>(queries, keys, values, Abf);
        proj_bf_kernel<<<dim3(64, 16, 3), 256, 0, stream>>>(Abf, Wt, bq, bk, bv, Qs);
    } else {
        proj_f32_kernel<<<dim3(64, 16, 3), 256, 0, stream>>>(queries, keys, values, Wt, bq, bk, bv, Qs);
    }
    vtrans_kernel<<<dim3(16, 128), 256, 0, stream>>>(Vs, Vtb);
    maskpack_kernel<<<dim3(2048), 256, 0, stream>>>(mask, flag, Mb, 2 * 1024 * 1024);
    attn_kernel<<<dim3(1024), 512, 0, stream>>>(Qs, Ksb, Vtb, attw, Mb, AO);
    outproj_kernel<<<dim3(64, 16), 256, 0, stream>>>(AO, Wt + (size_t)3 * 1024 * 1024, bo, (float*)d_out);
}

// Round 6
// 419.136 us; speedup vs baseline: 2.2955x; 1.6074x over previous
//
#include <hip/hip_runtime.h>
#include <hip/hip_bf16.h>

// ---------- types ----------
using short8 = __attribute__((ext_vector_type(8))) short;
using f32x4  = __attribute__((ext_vector_type(4))) float;

// f32 -> bf16 round-to-nearest-even
__device__ __forceinline__ unsigned short f2bf(float f) {
    union { float f; unsigned u; } x; x.f = f;
    unsigned r = x.u + 0x7FFFu + ((x.u >> 16) & 1u);
    return (unsigned short)(r >> 16);
}

// async global->LDS, 16B per lane; lds base must be wave-uniform
__device__ __forceinline__ void gload_lds16(const void* g, void* l) {
    __builtin_amdgcn_global_load_lds(
        (const __attribute__((address_space(1))) unsigned int*)g,
        (__attribute__((address_space(3))) unsigned int*)l, 16, 0, 0);
}

// ---------- mask dtype detector ----------
__global__ void detect_mask_kernel(const unsigned int* __restrict__ m, int* __restrict__ flag) {
    if (threadIdx.x == 0) *flag = 0;
    __syncthreads();
    unsigned v = m[threadIdx.x];
    if (v > 1u) {
        atomicOr(flag, 1);
        if (v != 0x3F800000u) atomicOr(flag, 2);
    }
}

// ---------- pack mask into bitmask (grid-stride) ----------
__global__ __launch_bounds__(256) void maskpack_kernel(
    const void* __restrict__ mask, const int* __restrict__ flag,
    unsigned long long* __restrict__ Mb, int nwords)
{
    const int l = threadIdx.x & 63;
    const int gwave = (int)((blockIdx.x * 256 + threadIdx.x) >> 6);
    const int nw = (int)((gridDim.x * 256) >> 6);
    const bool bytem = ((*flag) & 2) != 0;
    const unsigned char* m8 = (const unsigned char*)mask;
    const unsigned int* m32 = (const unsigned int*)mask;
    for (int w0 = gwave * 4; w0 < nwords; w0 += nw * 4) {
        unsigned v[4];
#pragma unroll
        for (int u = 0; u < 4; u++) {
            size_t e = (size_t)(w0 + u) * 64 + l;
            v[u] = bytem ? (unsigned)m8[e] : m32[e];
        }
#pragma unroll
        for (int u = 0; u < 4; u++) {
            unsigned long long b = __ballot(v[u] != 0u);
            if (l == 0) Mb[w0 + u] = b;
        }
    }
}

// ---------- transpose-convert W (f32 [k][n]) -> Wt (bf16 [n][k]) ----------
__global__ __launch_bounds__(256) void wconv_kernel(
    const float* __restrict__ W0, const float* __restrict__ W1,
    const float* __restrict__ W2, const float* __restrict__ W3,
    unsigned short* __restrict__ Wt)
{
    const int z = blockIdx.z;
    const float* W = (z == 0) ? W0 : ((z == 1) ? W1 : ((z == 2) ? W2 : W3));
    unsigned short* O = Wt + (size_t)z * 1024 * 1024;
    __shared__ float tile[64][68];
    const int t = threadIdx.x;
    const int k0 = blockIdx.x * 64, n0 = blockIdx.y * 64;
    const int rr = t >> 4, cc = t & 15;
#pragma unroll
    for (int i = 0; i < 4; i++) {
        int row = rr + i * 16;
        float4 v = *reinterpret_cast<const float4*>(W + (size_t)(k0 + row) * 1024 + n0 + cc * 4);
        *reinterpret_cast<float4*>(&tile[row][cc * 4]) = v;
    }
    __syncthreads();
#pragma unroll
    for (int i = 0; i < 4; i++) {
        int rn = rr + i * 16;
        ushort4 ov;
        ov.x = f2bf(tile[cc * 4 + 0][rn]);
        ov.y = f2bf(tile[cc * 4 + 1][rn]);
        ov.z = f2bf(tile[cc * 4 + 2][rn]);
        ov.w = f2bf(tile[cc * 4 + 3][rn]);
        *reinterpret_cast<ushort4*>(O + (size_t)(n0 + rn) * 1024 + k0 + cc * 4) = ov;
    }
}

// ---------- convert f32 A -> bf16 A ----------
__global__ __launch_bounds__(256) void aconv_kernel(
    const float* __restrict__ Aq, const float* __restrict__ Ak, const float* __restrict__ Av,
    unsigned short* __restrict__ Out)
{
    const int z = blockIdx.y;
    const float* A = (z == 0) ? Aq : ((z == 1) ? Ak : Av);
    unsigned short* O = Out + (size_t)z * 8192 * 1024;
    size_t i = ((size_t)blockIdx.x * 256 + threadIdx.x) * 8;
    float4 v0 = *reinterpret_cast<const float4*>(A + i);
    float4 v1 = *reinterpret_cast<const float4*>(A + i + 4);
    short8 o;
    o[0] = (short)f2bf(v0.x); o[1] = (short)f2bf(v0.y);
    o[2] = (short)f2bf(v0.z); o[3] = (short)f2bf(v0.w);
    o[4] = (short)f2bf(v1.x); o[5] = (short)f2bf(v1.y);
    o[6] = (short)f2bf(v1.z); o[7] = (short)f2bf(v1.w);
    *reinterpret_cast<short8*>(O + i) = o;
}

// ---------- m97-style 128x128x(BK=32) GEMM core, C = A @ W^T ----------
// A [M][1024] bf16 row-major, W [N][1024] bf16 row-major (rows = C cols).
// 256 thr = 4 waves (2x2 of 64x64); LDS 2x(8KB A + 8KB B) staged via global_load_lds.
#define GEMM_CORE(A_PTR, W_PTR)                                                             \
    __shared__ unsigned short Ab[2][4096];                                                  \
    __shared__ unsigned short Bb[2][4096];                                                  \
    const int tid = threadIdx.x, w = tid >> 6, l = tid & 63, l16 = l & 15, g = l >> 4;      \
    const int wr = w >> 1, wc = w & 1;                                                      \
    const int row0 = blockIdx.x * 128, col0 = blockIdx.y * 128;                             \
    const int offs = tid * 16;                                                              \
    const char* gA0 = (const char*)(A_PTR) + (size_t)(row0 + (offs >> 6)) * 2048 + (offs & 63);          \
    const char* gA1 = (const char*)(A_PTR) + (size_t)(row0 + ((offs + 4096) >> 6)) * 2048 + (offs & 63); \
    const char* gB0 = (const char*)(W_PTR) + (size_t)(col0 + (offs >> 6)) * 2048 + (offs & 63);          \
    const char* gB1 = (const char*)(W_PTR) + (size_t)(col0 + ((offs + 4096) >> 6)) * 2048 + (offs & 63); \
    char* ldsAw0 = (char*)Ab[0] + w * 1024; char* ldsAw0b = (char*)Ab[0] + 4096 + w * 1024; \
    char* ldsAw1 = (char*)Ab[1] + w * 1024; char* ldsAw1b = (char*)Ab[1] + 4096 + w * 1024; \
    char* ldsBw0 = (char*)Bb[0] + w * 1024; char* ldsBw0b = (char*)Bb[0] + 4096 + w * 1024; \
    char* ldsBw1 = (char*)Bb[1] + w * 1024; char* ldsBw1b = (char*)Bb[1] + 4096 + w * 1024; \
    const char* rdA = (char*)Ab[0] + (wr * 64 + l16) * 64 + g * 16;   /* +fr*1024, +buf*8192 */ \
    const char* rdB = (char*)Bb[0] + (wc * 64 + l16) * 64 + g * 16;                         \
    f32x4 acc[4][4];                                                                        \
    _Pragma("unroll")                                                                       \
    for (int i = 0; i < 4; i++)                                                             \
        _Pragma("unroll")                                                                   \
        for (int j = 0; j < 4; j++) acc[i][j] = (f32x4){0.f, 0.f, 0.f, 0.f};                \
    gload_lds16(gA0, ldsAw0); gload_lds16(gA1, ldsAw0b);                                    \
    gload_lds16(gB0, ldsBw0); gload_lds16(gB1, ldsBw0b);                                    \
    asm volatile("s_waitcnt vmcnt(0)" ::: "memory");                                        \
    __builtin_amdgcn_s_barrier();                                                           \
    for (int kt = 0; kt < 32; kt++) {                                                       \
        const int buf = kt & 1;                                                             \
        if (kt < 31) {                                                                      \
            const int ko = (kt + 1) * 64;                                                   \
            if (buf == 0) {                                                                 \
                gload_lds16(gA0 + ko, ldsAw1); gload_lds16(gA1 + ko, ldsAw1b);              \
                gload_lds16(gB0 + ko, ldsBw1); gload_lds16(gB1 + ko, ldsBw1b);              \
            } else {                                                                        \
                gload_lds16(gA0 + ko, ldsAw0); gload_lds16(gA1 + ko, ldsAw0b);              \
                gload_lds16(gB0 + ko, ldsBw0); gload_lds16(gB1 + ko, ldsBw0b);              \
            }                                                                               \
        }                                                                                   \
        short8 af[4], bfm[4];                                                               \
        _Pragma("unroll")                                                                   \
        for (int fr = 0; fr < 4; fr++)                                                      \
            af[fr] = *reinterpret_cast<const short8*>(rdA + buf * 8192 + fr * 1024);        \
        _Pragma("unroll")                                                                   \
        for (int fc = 0; fc < 4; fc++)                                                      \
            bfm[fc] = *reinterpret_cast<const short8*>(rdB + buf * 8192 + fc * 1024);       \
        _Pragma("unroll")                                                                   \
        for (int fr = 0; fr < 4; fr++)                                                      \
            _Pragma("unroll")                                                               \
            for (int fc = 0; fc < 4; fc++)                                                  \
                acc[fr][fc] = __builtin_amdgcn_mfma_f32_16x16x32_bf16(af[fr], bfm[fc], acc[fr][fc], 0, 0, 0); \
        asm volatile("s_waitcnt vmcnt(0)" ::: "memory");                                    \
        __builtin_amdgcn_s_barrier();                                                       \
    }

// ---------- projections: Out_z = A_z @ W_z^T + b_z -> bf16 [b][h][n][64] ----------
__global__ __launch_bounds__(256, 3) void gemm_proj_kernel(
    const unsigned short* __restrict__ Abf,  // [3][8192][1024]
    const unsigned short* __restrict__ Wt,   // [3][1024 n][1024 k]
    const float* __restrict__ bq, const float* __restrict__ bk, const float* __restrict__ bv,
    unsigned short* __restrict__ Out)        // [3][8][16][1024][64]
{
    const int z = blockIdx.z;
    const unsigned short* A = Abf + (size_t)z * 8192 * 1024;
    const unsigned short* Wz = Wt + (size_t)z * 1024 * 1024;
    const float* bias = (z == 0) ? bq : ((z == 1) ? bk : bv);
    unsigned short* Oz = Out + (size_t)z * 8 * 16 * 1024 * 64;

    GEMM_CORE(A, Wz)

#pragma unroll
    for (int fr = 0; fr < 4; fr++)
#pragma unroll
        for (int fc = 0; fc < 4; fc++)
#pragma unroll
            for (int r = 0; r < 4; r++) {
                int row = row0 + wr * 64 + fr * 16 + g * 4 + r;
                int col = col0 + wc * 64 + fc * 16 + l16;
                float val = acc[fr][fc][r] + bias[col];
                int bb = row >> 10, n = row & 1023;
                int h = col >> 6, d = col & 63;
                Oz[(((size_t)(bb * 16 + h)) * 1024 + n) * 64 + d] = f2bf(val);
            }
}

// ---------- output projection: d_out = AO @ Wo^T + bo (f32 out) ----------
__global__ __launch_bounds__(256, 3) void gemm_out_kernel(
    const unsigned short* __restrict__ Ain,  // [8192][1024] bf16
    const unsigned short* __restrict__ Wto,  // [1024 n][1024 k] bf16
    const float* __restrict__ bo,
    float* __restrict__ Out)                 // [8192][1024] f32
{
    GEMM_CORE(Ain, Wto)

#pragma unroll
    for (int fr = 0; fr < 4; fr++)
#pragma unroll
        for (int fc = 0; fc < 4; fc++)
#pragma unroll
            for (int r = 0; r < 4; r++) {
                int row = row0 + wr * 64 + fr * 16 + g * 4 + r;
                int col = col0 + wc * 64 + fc * 16 + l16;
                Out[(size_t)row * 1024 + col] = acc[fr][fc][r] + bo[col];
            }
}

// ---------- projection GEMM (f32 A fallback, converts in-loop) ----------
__global__ __launch_bounds__(256) void proj_f32_kernel(
    const float* __restrict__ Aq, const float* __restrict__ Ak, const float* __restrict__ Av,
    const unsigned short* __restrict__ Wt,
    const float* __restrict__ bq, const float* __restrict__ bk, const float* __restrict__ bv,
    unsigned short* __restrict__ Out)
{
    const int z = blockIdx.z;
    const float* A = (z == 0) ? Aq : ((z == 1) ? Ak : Av);
    const float* bias = (z == 0) ? bq : ((z == 1) ? bk : bv);
    const unsigned short* Wz = Wt + (size_t)z * 1024 * 1024;
    unsigned short* Oz = Out + (size_t)z * 8 * 16 * 1024 * 64;

    const int tid = threadIdx.x;
    const int w = tid >> 6, l = tid & 63;
    const int l16 = l & 15, g = l >> 4;
    const int rbase = blockIdx.x * 128 + w * 32;
    const int cbase = blockIdx.y * 64;

    f32x4 acc[2][4];
#pragma unroll
    for (int i = 0; i < 2; i++)
#pragma unroll
        for (int j = 0; j < 4; j++) acc[i][j] = (f32x4){0.f, 0.f, 0.f, 0.f};

#pragma unroll 2
    for (int k0 = 0; k0 < 1024; k0 += 32) {
        short8 a[2];
#pragma unroll
        for (int rf = 0; rf < 2; rf++) {
            const float* ap = A + (size_t)(rbase + rf * 16 + l16) * 1024 + k0 + g * 8;
            float4 v0 = *reinterpret_cast<const float4*>(ap);
            float4 v1 = *reinterpret_cast<const float4*>(ap + 4);
            short8 av;
            av[0] = (short)f2bf(v0.x); av[1] = (short)f2bf(v0.y);
            av[2] = (short)f2bf(v0.z); av[3] = (short)f2bf(v0.w);
            av[4] = (short)f2bf(v1.x); av[5] = (short)f2bf(v1.y);
            av[6] = (short)f2bf(v1.z); av[7] = (short)f2bf(v1.w);
            a[rf] = av;
        }
        short8 bfr[4];
#pragma unroll
        for (int cf = 0; cf < 4; cf++)
            bfr[cf] = *reinterpret_cast<const short8*>(Wz + (size_t)(cbase + cf * 16 + l16) * 1024 + k0 + g * 8);
#pragma unroll
        for (int rf = 0; rf < 2; rf++)
#pragma unroll
            for (int cf = 0; cf < 4; cf++)
                acc[rf][cf] = __builtin_amdgcn_mfma_f32_16x16x32_bf16(a[rf], bfr[cf], acc[rf][cf], 0, 0, 0);
    }

#pragma unroll
    for (int rf = 0; rf < 2; rf++)
#pragma unroll
        for (int cf = 0; cf < 4; cf++)
#pragma unroll
            for (int r = 0; r < 4; r++) {
                int row = rbase + rf * 16 + g * 4 + r;
                int col = cbase + cf * 16 + l16;
                float val = acc[rf][cf][r] + bias[col];
                int bb = row >> 10, n = row & 1023;
                int h = col >> 6, d = col & 63;
                Oz[(((size_t)(bb * 16 + h)) * 1024 + n) * 64 + d] = f2bf(val);
            }
}

// ---------- transpose V: Vs [bh][k][64 d] -> Vt [bh][64 d][1024 k] ----------
__global__ __launch_bounds__(256) void vtrans_kernel(
    const unsigned short* __restrict__ Vs, unsigned short* __restrict__ Vt)
{
    const int bh = blockIdx.y;
    const int k0 = blockIdx.x * 64;
    const unsigned short* In = Vs + (size_t)bh * 1024 * 64;
    unsigned short* O = Vt + (size_t)bh * 64 * 1024;
    __shared__ unsigned short tile[64][72];
    const int t = threadIdx.x;
    {
        const int row = t >> 3;
        const int c8 = (t & 7) * 8;
#pragma unroll
        for (int i = 0; i < 2; i++) {
            int r = row + i * 32;
            short8 v = *reinterpret_cast<const short8*>(In + (size_t)(k0 + r) * 64 + c8);
            *reinterpret_cast<short8*>(&tile[r][c8]) = v;
        }
    }
    __syncthreads();
    {
        const int rd = t >> 4, c4 = (t & 15) * 4;
#pragma unroll
        for (int i = 0; i < 4; i++) {
            int d = rd + i * 16;
            ushort4 ov;
            ov.x = tile[c4 + 0][d];
            ov.y = tile[c4 + 1][d];
            ov.z = tile[c4 + 2][d];
            ov.w = tile[c4 + 3][d];
            *reinterpret_cast<ushort4*>(O + (size_t)d * 1024 + k0 + c4) = ov;
        }
    }
}

// ---------- fused attention: 8 waves, LDS-staged K/V (global_load_lds, swizzled),
// counted vmcnt(5) so the 2-tile-lead attw/mask stream is never drained ----------
__global__ __launch_bounds__(512, 4) void attn_kernel(
    const unsigned short* __restrict__ Qs,     // [bh][1024][64]
    const unsigned short* __restrict__ Ks,     // [bh][1024][64]
    const unsigned short* __restrict__ Vt,     // [bh][64 d][1024 k]
    const float* __restrict__ attw,            // [bh][1024][1024]
    const unsigned long long* __restrict__ Mb, // [bh*1024 rows][16 words]
    unsigned short* __restrict__ AO)           // [b][q][h*64+d] bf16
{
    // LDS: K dbuf @0/8192, V dbuf @16384/24576, P @32768 (per wave 16x72 ushort = 2304B)
    __shared__ char smem[51200];

    // XCD-bijective decode: 8 q-tiles sharing one (b,h) -> same XCD (K/V L2 locality)
    const int bid = blockIdx.x;
    const int xj = bid & 7, xp = bid >> 3;
    const int qt = xp & 7;
    const int gbh = (xp >> 3) * 8 + xj;        // = h + 16*b
    const int h = gbh & 15, b = gbh >> 4;
    const int bh = b * 16 + h;

    const int tid = threadIdx.x, w = tid >> 6, l = tid & 63, l16 = l & 15, g = l >> 4;
    const int myq = qt * 128 + w * 16 + l16;

    const unsigned short* Qbh = Qs + (size_t)bh * 65536;
    const char* Kb = (const char*)(Ks + (size_t)bh * 65536);
    const char* Vb = (const char*)(Vt + (size_t)bh * 65536);
    const float* wrow = attw + ((size_t)bh * 1024 + myq) * 1024;
    const unsigned long long* mrow = Mb + ((size_t)bh * 1024 + myq) * 16;

    // ---- staging geometry: 8KB tile, 8 waves x 1KB; linear LDS, pre-swizzled source
    const int srow = w * 8 + (l >> 3);                 // tile-local row staged by this lane
    const int sinn = ((l & 7) * 16) ^ (((l >> 3) & 7) << 4);
    const char* gK = Kb + (size_t)srow * 128 + sinn;   // +8192 per tile
    const char* gV = Vb + (size_t)srow * 2048 + sinn;  // +128 per tile
    char* ldsK0w = smem + 0     + w * 1024;
    char* ldsK1w = smem + 8192  + w * 1024;
    char* ldsV0w = smem + 16384 + w * 1024;
    char* ldsV1w = smem + 24576 + w * 1024;

    // ---- ds_read addresses (swizzled): row=cf*16+l16 => row&7 == l16&7
    const int rswz = (l16 & 7) << 4;
    char* kaddrA = smem + l16 * 128 + ((g * 16) ^ rswz);        // ks=0; +cf*2048, +BUF*8192
    char* kaddrB = smem + l16 * 128 + ((64 + g * 16) ^ rswz);   // ks=1
    char* pw = smem + 32768 + w * 2304 + l16 * 144 + g * 8;     // P write: +cf*32
    char* pr = smem + 32768 + w * 2304 + l16 * 144 + g * 16;    // P read:  +ks*64

    short8 qf0 = *reinterpret_cast<const short8*>(Qbh + (size_t)myq * 64 + g * 8);
    short8 qf1 = *reinterpret_cast<const short8*>(Qbh + (size_t)myq * 64 + 32 + g * 8);

    float4 wvA[4], wvB[4];
    unsigned long long mbA, mbB;

    // prologue: stage tile0 (2 GLL) then wv(0), wv(1) (10 loads); retire staging only
    gload_lds16(gK, ldsK0w);
    gload_lds16(gV, ldsV0w);
    gK += 8192; gV += 128;
#pragma unroll
    for (int cf = 0; cf < 4; cf++)
        wvA[cf] = *reinterpret_cast<const float4*>(wrow + cf * 16 + g * 4);
    mbA = mrow[0];
#pragma unroll
    for (int cf = 0; cf < 4; cf++)
        wvB[cf] = *reinterpret_cast<const float4*>(wrow + 64 + cf * 16 + g * 4);
    mbB = mrow[1];
    asm volatile("s_waitcnt vmcnt(10)" ::: "memory");
    __builtin_amdgcn_s_barrier();
    __builtin_amdgcn_sched_barrier(0);

    f32x4 accO[4];
#pragma unroll
    for (int j = 0; j < 4; j++) accO[j] = (f32x4){0.f, 0.f, 0.f, 0.f};
    float den = 0.f;

    // per tile: [stage(t+1): 2 GLL] [QK+softmax using wv(t)] [refill wv(t+2): 5 loads]
    //           [PV] [vmcnt(5): retire wv(t+1)+stage(t+1), keep wv(t+2)] [barrier]
#define ATTN_ITER(KT, BUF, WVC, MBC)                                                        \
    {                                                                                       \
        if ((KT) < 15) {                                                                    \
            gload_lds16(gK, (BUF) ? ldsK0w : ldsK1w);                                       \
            gload_lds16(gV, (BUF) ? ldsV0w : ldsV1w);                                       \
        }                                                                                   \
        gK += 8192; gV += 128;                                                              \
        _Pragma("unroll")                                                                   \
        for (int cf = 0; cf < 4; cf++) {                                                    \
            short8 k0 = *reinterpret_cast<const short8*>(kaddrA + (BUF) * 8192 + cf * 2048);\
            short8 k1 = *reinterpret_cast<const short8*>(kaddrB + (BUF) * 8192 + cf * 2048);\
            f32x4 s = (f32x4){0.f, 0.f, 0.f, 0.f};                                          \
            s = __builtin_amdgcn_mfma_f32_16x16x32_bf16(k0, qf0, s, 0, 0, 0);               \
            s = __builtin_amdgcn_mfma_f32_16x16x32_bf16(k1, qf1, s, 0, 0, 0);               \
            unsigned mn = (unsigned)((MBC) >> (cf * 16 + g * 4)) & 0xFu;                    \
            float p0 = (mn & 1u) ? 0.f : __expf(s[0] * 0.125f * (WVC)[cf].x);               \
            float p1 = (mn & 2u) ? 0.f : __expf(s[1] * 0.125f * (WVC)[cf].y);               \
            float p2 = (mn & 4u) ? 0.f : __expf(s[2] * 0.125f * (WVC)[cf].z);               \
            float p3 = (mn & 8u) ? 0.f : __expf(s[3] * 0.125f * (WVC)[cf].w);               \
            den += p0 + p1 + p2 + p3;                                                       \
            ushort4 pwv;                                                                    \
            pwv.x = f2bf(p0); pwv.y = f2bf(p1); pwv.z = f2bf(p2); pwv.w = f2bf(p3);         \
            *reinterpret_cast<ushort4*>(pw + cf * 32) = pwv;                                \
        }                                                                                   \
        {                                                                                   \
            const int ktn = ((KT) + 2) & 15;                                                \
            _Pragma("unroll")                                                               \
            for (int cf = 0; cf < 4; cf++)                                                  \
                (WVC)[cf] = *reinterpret_cast<const float4*>(wrow + ktn * 64 + cf * 16 + g * 4); \
            (MBC) = mrow[ktn];                                                              \
        }                                                                                   \
        {                                                                                   \
            short8 pf0 = *reinterpret_cast<const short8*>(pr);                              \
            short8 pf1 = *reinterpret_cast<const short8*>(pr + 64);                         \
            _Pragma("unroll")                                                               \
            for (int cf = 0; cf < 4; cf++) {                                                \
                short8 v0 = *reinterpret_cast<const short8*>(kaddrA + 16384 + (BUF) * 8192 + cf * 2048); \
                short8 v1 = *reinterpret_cast<const short8*>(kaddrB + 16384 + (BUF) * 8192 + cf * 2048); \
                accO[cf] = __builtin_amdgcn_mfma_f32_16x16x32_bf16(pf0, v0, accO[cf], 0, 0, 0); \
                accO[cf] = __builtin_amdgcn_mfma_f32_16x16x32_bf16(pf1, v1, accO[cf], 0, 0, 0); \
            }                                                                               \
        }                                                                                   \
        asm volatile("s_waitcnt vmcnt(5)" ::: "memory");                                    \
        __builtin_amdgcn_s_barrier();                                                       \
        __builtin_amdgcn_sched_barrier(0);                                                  \
    }

    for (int kt2 = 0; kt2 < 16; kt2 += 2) {
        ATTN_ITER(kt2, 0, wvA, mbA);
        ATTN_ITER(kt2 + 1, 1, wvB, mbB);
    }
#undef ATTN_ITER

    den += __shfl_xor(den, 16);
    den += __shfl_xor(den, 32);

#pragma unroll
    for (int r = 0; r < 4; r++) {
        float dr = __shfl(den, g * 4 + r);
        float inv = 1.0f / dr;
#pragma unroll
        for (int cf = 0; cf < 4; cf++) {
            int qrow = qt * 128 + w * 16 + g * 4 + r;
            int col = h * 64 + cf * 16 + l16;
            AO[((size_t)b * 1024 + qrow) * 1024 + col] = f2bf(accO[cf][r] * inv);
        }
    }
}

extern "C" void kernel_launch(void* const* d_in, const int* in_sizes, int n_in,
                              void* d_out, int out_size, void* d_ws, size_t ws_size,
                              hipStream_t stream)
{
    const float* queries = (const float*)d_in[0];
    const float* keys    = (const float*)d_in[1];
    const float* values  = (const float*)d_in[2];
    const void*  mask    = d_in[3];
    const float* attw    = (const float*)d_in[4];
    const float* Wq = (const float*)d_in[5];
    const float* bq = (const float*)d_in[6];
    const float* Wk = (const float*)d_in[7];
    const float* bk = (const float*)d_in[8];
    const float* Wv = (const float*)d_in[9];
    const float* bv = (const float*)d_in[10];
    const float* Wo = (const float*)d_in[11];
    const float* bo = (const float*)d_in[12];

    char* ws = (char*)d_ws;
    int* flag = (int*)ws;
    unsigned short* base = (unsigned short*)(ws + 256);
    const size_t M8 = (size_t)8 * 1024 * 1024;
    unsigned short* Qs  = base;
    unsigned short* Ksb = base + M8;
    unsigned short* Vs  = base + 2 * M8;         // raw V proj; dead after vtrans -> reused for Mb
    unsigned short* Vtb = base + 3 * M8;
    unsigned short* AO  = base + 4 * M8;
    unsigned short* Wt  = base + 5 * M8;
    unsigned short* Abf = base + 5 * M8 + 4 * 1024 * 1024;
    unsigned long long* Mb = (unsigned long long*)Vs;
    const size_t need_abf = 256 + (5 * M8 + 4 * 1024 * 1024 + 3 * M8) * sizeof(unsigned short);
    const bool useAbf = ws_size >= need_abf;

    detect_mask_kernel<<<1, 256, 0, stream>>>((const unsigned int*)mask, flag);
    wconv_kernel<<<dim3(16, 16, 4), 256, 0, stream>>>(Wq, Wk, Wv, Wo, Wt);
    if (useAbf) {
        aconv_kernel<<<dim3(4096, 3), 256, 0, stream>>>(queries, keys, values, Abf);
        gemm_proj_kernel<<<dim3(64, 8, 3), 256, 0, stream>>>(Abf, Wt, bq, bk, bv, Qs);
    } else {
        proj_f32_kernel<<<dim3(64, 16, 3), 256, 0, stream>>>(queries, keys, values, Wt, bq, bk, bv, Qs);
    }
    vtrans_kernel<<<dim3(16, 128), 256, 0, stream>>>(Vs, Vtb);
    maskpack_kernel<<<dim3(2048), 256, 0, stream>>>(mask, flag, Mb, 2 * 1024 * 1024);
    attn_kernel<<<dim3(1024), 512, 0, stream>>>(Qs, Ksb, Vtb, attw, Mb, AO);
    gemm_out_kernel<<<dim3(64, 8), 256, 0, stream>>>(AO, Wt + (size_t)3 * 1024 * 1024, bo, (float*)d_out);
}